// Round 2
// baseline (787.366 us; speedup 1.0000x reference)
//
#include <hip/hip_runtime.h>

#define NA 150381
#define NC 90
#define PK 1024
#define CMAX 4096
#define MDET 100
#define STHR 0.996f
#define NTHR 0.5f
#define IMGF 896.0f

typedef unsigned long long u64;

// ---------------- decode boxes + translation ----------------
__global__ void k_decode(const float* __restrict__ anc, const float* __restrict__ reg,
                         const float* __restrict__ ta, const float* __restrict__ td,
                         float* __restrict__ boxes, float* __restrict__ trn) {
  int i = blockIdx.x * blockDim.x + threadIdx.x;
  if (i >= NA) return;
  float a0 = anc[i*4+0], a1 = anc[i*4+1], a2 = anc[i*4+2], a3 = anc[i*4+3];
  float cxa = (a0 + a2) * 0.5f, cya = (a1 + a3) * 0.5f;
  float wa = a2 - a0, ha = a3 - a1;
  float ty = reg[i*4+0], tx = reg[i*4+1], th = reg[i*4+2], tw = reg[i*4+3];
  float w = expf(tw) * wa, h = expf(th) * ha;
  float cy = ty * ha + cya, cx = tx * wa + cxa;
  float x1 = cx - w * 0.5f, y1 = cy - h * 0.5f;
  float x2 = cx + w * 0.5f, y2 = cy + h * 0.5f;
  x1 = fminf(fmaxf(x1, 0.f), IMGF); y1 = fminf(fmaxf(y1, 0.f), IMGF);
  x2 = fminf(fmaxf(x2, 0.f), IMGF); y2 = fminf(fmaxf(y2, 0.f), IMGF);
  boxes[i*4+0] = x1; boxes[i*4+1] = y1; boxes[i*4+2] = x2; boxes[i*4+3] = y2;
  float st = ta[i*3+2];
  trn[i*3+0] = ta[i*3+0] + td[i*3+0] * st;
  trn[i*3+1] = ta[i*3+1] + td[i*3+1] * st;
  trn[i*3+2] = td[i*3+2];
}

// ---------------- threshold filter into per-class candidate lists ----------------
__global__ void k_collect(const float* __restrict__ cls, int* __restrict__ counts,
                          u64* __restrict__ cand) {
  const int total = NA * NC;
  for (int f = blockIdx.x * blockDim.x + threadIdx.x; f < total; f += gridDim.x * blockDim.x) {
    float v = cls[f];
    if (v > STHR) {
      int c = f % NC;
      int i = f / NC;
      int pos = atomicAdd(&counts[c], 1);
      if (pos < CMAX) {
        // key: score desc, anchor index asc (matches lax.top_k stable tie-break)
        cand[(size_t)c * CMAX + pos] =
            ((u64)__float_as_uint(v) << 32) | (u64)(0xFFFFFFFFu - (unsigned)i);
      }
    }
  }
}

__device__ __forceinline__ void bitonic_desc(u64* a, int n, int tid, int nth) {
  for (int k = 2; k <= n; k <<= 1) {
    for (int j = k >> 1; j > 0; j >>= 1) {
      __syncthreads();
      for (int i = tid; i < n; i += nth) {
        int ixj = i ^ j;
        if (ixj > i) {
          u64 x = a[i], y = a[ixj];
          if (((i & k) == 0) ? (x < y) : (x > y)) { a[i] = y; a[ixj] = x; }
        }
      }
    }
  }
  __syncthreads();
}

// ---------------- per-class sort (adaptive bitonic, descending) -> top-1024 ----------------
__global__ __launch_bounds__(1024) void k_sortclass(const int* __restrict__ counts,
                                                    const u64* __restrict__ cand,
                                                    u64* __restrict__ topk,
                                                    int* __restrict__ mcount) {
  __shared__ u64 buf[CMAX];
  const int c = blockIdx.x, tid = threadIdx.x;
  int M = min(counts[c], CMAX);
  int NS = PK;                     // smallest pow2 >= M, at least PK
  while (NS < M) NS <<= 1;
  for (int k = tid; k < NS; k += blockDim.x)
    buf[k] = (k < M) ? cand[(size_t)c * CMAX + k] : 0ULL;
  bitonic_desc(buf, NS, tid, blockDim.x);
  for (int k = tid; k < PK; k += blockDim.x) topk[(size_t)c * PK + k] = buf[k];
  if (tid == 0) mcount[c] = min(M, PK);
}

// ---------------- per-class NMS: parallel suppression matrix + 1-wave serial scan ----------------
__global__ __launch_bounds__(1024) void k_nms(const u64* __restrict__ topk,
                                              const int* __restrict__ mcount,
                                              const float* __restrict__ boxes,
                                              unsigned* __restrict__ keep_out) {
  extern __shared__ unsigned sup[];              // [PK][32] bit-matrix, 128 KB
  __shared__ float bx1[PK], by1[PK], bx2[PK], by2[PK], ar[PK];
  const int c = blockIdx.x, tid = threadIdx.x;
  const int M = mcount[c];
  for (int t = tid; t < M; t += 1024) {
    u64 key = topk[(size_t)c * PK + t];
    unsigned aidx = 0xFFFFFFFFu - (unsigned)(key & 0xFFFFFFFFull);
    float x1 = boxes[aidx*4+0], y1 = boxes[aidx*4+1];
    float x2 = boxes[aidx*4+2], y2 = boxes[aidx*4+3];
    bx1[t] = x1; by1[t] = y1; bx2[t] = x2; by2[t] = y2;
    ar[t] = (x2 - x1) * (y2 - y1);
  }
  __syncthreads();
  // build suppression rows: sup[i][w] bit b set iff j=w*32+b > i and iou(i,j) > thr
  for (int t = tid; t < M * 32; t += 1024) {
    int i = t >> 5, w = t & 31;
    float x1 = bx1[i], y1 = by1[i], x2 = bx2[i], y2 = by2[i], ai = ar[i];
    unsigned word = 0;
    int jb = w << 5;
    int jend = min(M - jb, 32);
    for (int b = 0; b < jend; ++b) {
      int j = jb + b;
      if (j > i) {
        float ix1 = fmaxf(x1, bx1[j]), iy1 = fmaxf(y1, by1[j]);
        float ix2 = fminf(x2, bx2[j]), iy2 = fminf(y2, by2[j]);
        float iw = fmaxf(ix2 - ix1, 0.f), ih = fmaxf(iy2 - iy1, 0.f);
        float inter = iw * ih;
        float uni = ai + ar[j] - inter;
        if (inter / fmaxf(uni, 1e-9f) > NTHR) word |= 1u << b;
      }
    }
    sup[(i << 5) + w] = word;
  }
  __syncthreads();
  // serial greedy scan, one wave, keep words in registers, no barriers
  if (tid < 32) {
    int lo = tid * 32;
    unsigned kw = (M <= lo) ? 0u : ((M - lo >= 32) ? 0xFFFFFFFFu : ((1u << (M - lo)) - 1u));
    for (int i = 0; i < M; ++i) {
      unsigned ow = __shfl(kw, i >> 5);
      if ((ow >> (i & 31)) & 1u) kw &= ~sup[(i << 5) + tid];
    }
    keep_out[c * 32 + tid] = kw;
  }
}

// ---------------- global top-100 via radix-select + small sort + gather ----------------
__global__ __launch_bounds__(1024) void k_final(const u64* __restrict__ topk,
                                                const unsigned* __restrict__ keep,
                                                const float* __restrict__ boxes,
                                                const float* __restrict__ rot,
                                                const float* __restrict__ trn,
                                                float* __restrict__ out) {
  extern __shared__ u64 buf[];                       // 16384 u64 = 131072 B
  u64* cand = buf;                                   // slots [0, 9000)
  unsigned* hist = (unsigned*)(buf + 9216);          // 8448 u32 bins
  u64* sbuf = (u64*)((char*)buf + 9216*8 + 8448*4);  // 1024 u64
  __shared__ unsigned sscan[1024];
  __shared__ int s_B, s_gc, s_gcnt;

  const int tid = threadIdx.x;
  const unsigned SB = __float_as_uint(STHR);
  const int NB = (int)((0x3F800000u - SB) >> 3) + 1;  // ~8390 bins

  for (int t = tid; t < NC * MDET; t += 1024) cand[t] = 0ULL;
  for (int t = tid; t < NB; t += 1024) hist[t] = 0u;
  if (tid == 0) s_gcnt = 0;
  __syncthreads();

  // collect first <=100 kept per class (positions ascending == scores descending)
  const int wave = tid >> 6;
  const int lane = tid & 63;
  for (int c = wave; c < NC; c += 16) {
    if (lane < 32) {
      unsigned w = keep[c * 32 + lane];
      int pc = __popc(w);
      int scan = pc;
      for (int d = 1; d < 32; d <<= 1) {
        int v = __shfl_up(scan, d);
        if (lane >= d) scan += v;
      }
      int base = scan - pc;  // exclusive prefix of kept count
      unsigned ww = w;
      while (ww) {
        int b = __ffs(ww) - 1;
        ww &= ww - 1u;
        if (base < MDET) {
          int pos = lane * 32 + b;
          u64 tkey = topk[(size_t)c * PK + pos];
          unsigned flat = (unsigned)(c * PK + pos);
          cand[c * MDET + base] =
              (tkey & 0xFFFFFFFF00000000ull) | (u64)(0xFFFFFFFFu - flat);
        }
        base++;
      }
    }
  }
  __syncthreads();

  // histogram scores into bins
  for (int t = tid; t < NC * MDET; t += 1024) {
    u64 k = cand[t];
    if (k) atomicAdd(&hist[(int)(((unsigned)(k >> 32) - SB) >> 3)], 1u);
  }
  __syncthreads();

  // per-thread chunk sums + block suffix scan
  const int CH = (NB + 1023) >> 10;
  int clo = tid * CH, chi = min(clo + CH, NB);
  unsigned s = 0;
  for (int b = clo; b < chi; ++b) s += hist[b];
  sscan[tid] = s;
  __syncthreads();
  for (int d = 1; d < 1024; d <<= 1) {
    unsigned v = sscan[tid];
    unsigned add = (tid + d < 1024) ? sscan[tid + d] : 0u;
    __syncthreads();
    sscan[tid] = v + add;
    __syncthreads();
  }
  unsigned suff = sscan[tid];
  unsigned suffn = (tid < 1023) ? sscan[tid + 1] : 0u;
  if (tid == 0 && sscan[0] < MDET) { s_B = 0; s_gc = (int)sscan[0]; }
  if (suff >= MDET && (tid == 1023 || suffn < MDET)) {
    unsigned after = suffn;          // count in bins above this chunk
    int B = clo;
    for (int b = chi - 1; b >= clo; --b) {
      after += hist[b];
      if (after >= MDET) { B = b; break; }
    }
    s_B = B; s_gc = (int)after;
  }
  __syncthreads();
  const int B = s_B, gc = s_gc;

  u64* sel;
  if (gc <= 1024) {
    for (int t = tid; t < 1024; t += 1024) sbuf[t] = 0ULL;
    __syncthreads();
    for (int t = tid; t < NC * MDET; t += 1024) {
      u64 k = cand[t];
      if (k && (int)(((unsigned)(k >> 32) - SB) >> 3) >= B)
        sbuf[atomicAdd(&s_gcnt, 1)] = k;
    }
    __syncthreads();
    bitonic_desc(sbuf, 1024, tid, 1024);
    sel = sbuf;
  } else {
    // pathological tie-pileup: full sort fallback (hist/sbuf regions dead now)
    for (int t = tid; t < 16384; t += 1024)
      if (t >= NC * MDET) buf[t] = 0ULL;
    __syncthreads();
    bitonic_desc(buf, 16384, tid, 1024);
    sel = buf;
  }

  // gather top-100 outputs
  if (tid < MDET) {
    u64 key = sel[tid];
    bool ok = (key != 0ULL);
    float b0 = -1.f, b1 = -1.f, b2 = -1.f, b3 = -1.f;
    float r0 = -1.f, r1 = -1.f, r2 = -1.f;
    float t0 = -1.f, t1 = -1.f, t2 = -1.f;
    float sc = -1.f, lab = -1.f;
    if (ok) {
      float score = __uint_as_float((unsigned)(key >> 32));
      unsigned flat = 0xFFFFFFFFu - (unsigned)(key & 0xFFFFFFFFull);
      int c = flat >> 10, pos = flat & 1023;
      u64 tkey = topk[(size_t)c * PK + pos];
      unsigned aidx = 0xFFFFFFFFu - (unsigned)(tkey & 0xFFFFFFFFull);
      b0 = boxes[aidx*4+0]; b1 = boxes[aidx*4+1];
      b2 = boxes[aidx*4+2]; b3 = boxes[aidx*4+3];
      sc = score; lab = (float)c;
      r0 = rot[aidx*3+0]; r1 = rot[aidx*3+1]; r2 = rot[aidx*3+2];
      t0 = trn[aidx*3+0]; t1 = trn[aidx*3+1]; t2 = trn[aidx*3+2];
    }
    out[tid*4+0] = b0; out[tid*4+1] = b1; out[tid*4+2] = b2; out[tid*4+3] = b3;
    out[400 + tid] = sc;
    out[500 + tid] = lab;
    out[600 + tid*3+0] = r0; out[600 + tid*3+1] = r1; out[600 + tid*3+2] = r2;
    out[900 + tid*3+0] = t0; out[900 + tid*3+1] = t1; out[900 + tid*3+2] = t2;
  }
}

extern "C" void kernel_launch(void* const* d_in, const int* in_sizes, int n_in,
                              void* d_out, int out_size, void* d_ws, size_t ws_size,
                              hipStream_t stream) {
  const float* anchors        = (const float*)d_in[0];
  const float* regression     = (const float*)d_in[1];
  const float* classification = (const float*)d_in[2];
  const float* rotation       = (const float*)d_in[3];
  const float* tanch          = (const float*)d_in[4];
  const float* tdelta         = (const float*)d_in[5];
  float* out = (float*)d_out;

  char* ws = (char*)d_ws;
  size_t off = 0;
  auto alloc = [&](size_t bytes) -> void* {
    void* p = ws + off;
    off += (bytes + 255) & ~(size_t)255;
    return p;
  };
  float*    boxes  = (float*)alloc((size_t)NA * 4 * 4);
  float*    trn    = (float*)alloc((size_t)NA * 3 * 4);
  int*      counts = (int*)alloc(NC * 4);
  int*      mcount = (int*)alloc(NC * 4);
  u64*      cand   = (u64*)alloc((size_t)NC * CMAX * 8);
  u64*      topk   = (u64*)alloc((size_t)NC * PK * 8);
  unsigned* keep   = (unsigned*)alloc(NC * 32 * 4);

  hipMemsetAsync(counts, 0, NC * 4, stream);

  k_decode<<<(NA + 255) / 256, 256, 0, stream>>>(anchors, regression, tanch, tdelta, boxes, trn);
  k_collect<<<2048, 256, 0, stream>>>(classification, counts, cand);
  k_sortclass<<<NC, 1024, 0, stream>>>(counts, cand, topk, mcount);

  hipFuncSetAttribute(reinterpret_cast<const void*>(k_nms),
                      hipFuncAttributeMaxDynamicSharedMemorySize, 131072);
  k_nms<<<NC, 1024, 131072, stream>>>(topk, mcount, boxes, keep);

  hipFuncSetAttribute(reinterpret_cast<const void*>(k_final),
                      hipFuncAttributeMaxDynamicSharedMemorySize, 131072);
  k_final<<<1, 1024, 131072, stream>>>(topk, keep, boxes, rotation, trn, out);
}

// Round 3
// 252.744 us; speedup vs baseline: 3.1153x; 3.1153x over previous
//
#include <hip/hip_runtime.h>

#define NA 150381
#define NC 90
#define PK 1024
#define CMAX 4096
#define MDET 100
#define STHR 0.996f
#define NTHR 0.5f
#define IMGF 896.0f
#define CPAD 32  // counts padded: one 128B cacheline per class

typedef unsigned long long u64;

// ---------------- decode boxes + translation ----------------
__global__ void k_decode(const float4* __restrict__ anc, const float4* __restrict__ reg,
                         const float* __restrict__ ta, const float* __restrict__ td,
                         float4* __restrict__ boxes, float* __restrict__ trn) {
  int i = blockIdx.x * blockDim.x + threadIdx.x;
  if (i >= NA) return;
  float4 a = anc[i];
  float4 r = reg[i];
  float cxa = (a.x + a.z) * 0.5f, cya = (a.y + a.w) * 0.5f;
  float wa = a.z - a.x, ha = a.w - a.y;
  float w = expf(r.w) * wa, h = expf(r.z) * ha;
  float cy = r.x * ha + cya, cx = r.y * wa + cxa;
  float4 b;
  b.x = fminf(fmaxf(cx - w * 0.5f, 0.f), IMGF);
  b.y = fminf(fmaxf(cy - h * 0.5f, 0.f), IMGF);
  b.z = fminf(fmaxf(cx + w * 0.5f, 0.f), IMGF);
  b.w = fminf(fmaxf(cy + h * 0.5f, 0.f), IMGF);
  boxes[i] = b;
  float st = ta[i*3+2];
  trn[i*3+0] = ta[i*3+0] + td[i*3+0] * st;
  trn[i*3+1] = ta[i*3+1] + td[i*3+1] * st;
  trn[i*3+2] = td[i*3+2];
}

// ---------------- threshold filter into per-class candidate lists ----------------
__global__ void k_collect(const float4* __restrict__ cls4, int* __restrict__ counts,
                          u64* __restrict__ cand) {
  const int total = NA * NC;
  const int nv4 = total >> 2;             // 3383572 full float4s, 2-elem tail
  const int stride = gridDim.x * blockDim.x;
  for (int q = blockIdx.x * blockDim.x + threadIdx.x; q < nv4; q += stride) {
    float4 v4 = cls4[q];
    float vv[4] = {v4.x, v4.y, v4.z, v4.w};
    #pragma unroll
    for (int e = 0; e < 4; ++e) {
      float v = vv[e];
      if (v > STHR) {
        int f = q * 4 + e;
        int c = f % NC;
        int i = f / NC;
        int pos = atomicAdd(&counts[c * CPAD], 1);
        if (pos < CMAX)
          cand[(size_t)c * CMAX + pos] =
              ((u64)__float_as_uint(v) << 32) | (u64)(0xFFFFFFFFu - (unsigned)i);
      }
    }
  }
  // tail
  int g = blockIdx.x * blockDim.x + threadIdx.x;
  if (g < total - nv4 * 4) {
    int f = nv4 * 4 + g;
    float v = ((const float*)cls4)[f];
    if (v > STHR) {
      int c = f % NC;
      int i = f / NC;
      int pos = atomicAdd(&counts[c * CPAD], 1);
      if (pos < CMAX)
        cand[(size_t)c * CMAX + pos] =
            ((u64)__float_as_uint(v) << 32) | (u64)(0xFFFFFFFFu - (unsigned)i);
    }
  }
}

__device__ __forceinline__ void bitonic_desc(u64* a, int n, int tid, int nth) {
  for (int k = 2; k <= n; k <<= 1) {
    for (int j = k >> 1; j > 0; j >>= 1) {
      __syncthreads();
      for (int i = tid; i < n; i += nth) {
        int ixj = i ^ j;
        if (ixj > i) {
          u64 x = a[i], y = a[ixj];
          if (((i & k) == 0) ? (x < y) : (x > y)) { a[i] = y; a[ixj] = x; }
        }
      }
    }
  }
  __syncthreads();
}

// ---------------- per-class sort (adaptive bitonic, descending) -> top-1024 ----------------
__global__ __launch_bounds__(1024) void k_sortclass(const int* __restrict__ counts,
                                                    const u64* __restrict__ cand,
                                                    u64* __restrict__ topk,
                                                    int* __restrict__ mcount) {
  __shared__ u64 buf[CMAX];
  const int c = blockIdx.x, tid = threadIdx.x;
  int M = min(counts[c * CPAD], CMAX);
  int NS = PK;                     // smallest pow2 >= M, at least PK
  while (NS < M) NS <<= 1;
  for (int k = tid; k < NS; k += blockDim.x)
    buf[k] = (k < M) ? cand[(size_t)c * CMAX + k] : 0ULL;
  bitonic_desc(buf, NS, tid, blockDim.x);
  for (int k = tid; k < PK; k += blockDim.x) topk[(size_t)c * PK + k] = buf[k];
  if (tid == 0) mcount[c] = min(M, PK);
}

// ---------------- per-class NMS: parallel suppression matrix + 1-wave serial scan ----------------
// Mapping: thread tid owns row i=tid. Per-lane reads bx*[tid] are stride-1
// (conflict-free); bx*[j] is wave-uniform (broadcast). Row stored sup[i*32+w].
__global__ __launch_bounds__(1024) void k_nms(const u64* __restrict__ topk,
                                              const int* __restrict__ mcount,
                                              const float4* __restrict__ boxes,
                                              unsigned* __restrict__ keep_out) {
  extern __shared__ unsigned sup[];              // [PK][32] bit-matrix, 128 KB
  __shared__ float bx1[PK], by1[PK], bx2[PK], by2[PK], ar[PK];
  const int c = blockIdx.x, tid = threadIdx.x;
  const int M = mcount[c];
  for (int t = tid; t < M; t += 1024) {
    u64 key = topk[(size_t)c * PK + t];
    unsigned aidx = 0xFFFFFFFFu - (unsigned)(key & 0xFFFFFFFFull);
    float4 b = boxes[aidx];
    bx1[t] = b.x; by1[t] = b.y; bx2[t] = b.z; by2[t] = b.w;
    ar[t] = (b.z - b.x) * (b.w - b.y);
  }
  __syncthreads();
  if (tid < M) {
    float x1 = bx1[tid], y1 = by1[tid], x2 = bx2[tid], y2 = by2[tid], ai = ar[tid];
    #pragma unroll 4
    for (int w = 0; w < 32; ++w) {
      unsigned word = 0;
      int jb = w << 5;
      if (jb + 31 > tid && jb < M) {       // skip all-zero lower-triangle words
        int jend = min(M - jb, 32);
        for (int b = 0; b < jend; ++b) {
          int j = jb + b;
          if (j > tid) {
            float ix1 = fmaxf(x1, bx1[j]), iy1 = fmaxf(y1, by1[j]);
            float ix2 = fminf(x2, bx2[j]), iy2 = fminf(y2, by2[j]);
            float iw = fmaxf(ix2 - ix1, 0.f), ih = fmaxf(iy2 - iy1, 0.f);
            float inter = iw * ih;
            float uni = ai + ar[j] - inter;
            if (inter / fmaxf(uni, 1e-9f) > NTHR) word |= 1u << b;
          }
        }
      }
      sup[(tid << 5) + w] = word;
    }
  }
  __syncthreads();
  // serial greedy scan, one wave, keep words in registers, no barriers
  if (tid < 32) {
    int lo = tid * 32;
    unsigned kw = (M <= lo) ? 0u : ((M - lo >= 32) ? 0xFFFFFFFFu : ((1u << (M - lo)) - 1u));
    for (int i = 0; i < M; ++i) {
      unsigned srow = sup[(i << 5) + tid];   // independent of kw chain: pipelines
      unsigned ow = __shfl(kw, i >> 5);
      if ((ow >> (i & 31)) & 1u) kw &= ~srow;
    }
    keep_out[c * 32 + tid] = kw;
  }
}

// ---------------- global top-100 via radix-select + small sort + gather ----------------
__global__ __launch_bounds__(1024) void k_final(const u64* __restrict__ topk,
                                                const unsigned* __restrict__ keep,
                                                const float4* __restrict__ boxes,
                                                const float* __restrict__ rot,
                                                const float* __restrict__ trn,
                                                float* __restrict__ out) {
  extern __shared__ u64 buf[];                       // 16384 u64 = 131072 B
  u64* cand = buf;                                   // slots [0, 9000)
  unsigned* hist = (unsigned*)(buf + 9216);          // 8448 u32 bins
  u64* sbuf = (u64*)((char*)buf + 9216*8 + 8448*4);  // 1024 u64
  __shared__ unsigned sscan[1024];
  __shared__ int s_B, s_gc, s_gcnt;

  const int tid = threadIdx.x;
  const unsigned SB = __float_as_uint(STHR);
  const int NB = (int)((0x3F800000u - SB) >> 3) + 1;  // ~8390 bins

  for (int t = tid; t < NC * MDET; t += 1024) cand[t] = 0ULL;
  for (int t = tid; t < NB; t += 1024) hist[t] = 0u;
  if (tid == 0) s_gcnt = 0;
  __syncthreads();

  // collect first <=100 kept per class (positions ascending == scores descending)
  const int wave = tid >> 6;
  const int lane = tid & 63;
  for (int c = wave; c < NC; c += 16) {
    if (lane < 32) {
      unsigned w = keep[c * 32 + lane];
      int pc = __popc(w);
      int scan = pc;
      for (int d = 1; d < 32; d <<= 1) {
        int v = __shfl_up(scan, d);
        if (lane >= d) scan += v;
      }
      int base = scan - pc;  // exclusive prefix of kept count
      unsigned ww = w;
      while (ww) {
        int b = __ffs(ww) - 1;
        ww &= ww - 1u;
        if (base < MDET) {
          int pos = lane * 32 + b;
          u64 tkey = topk[(size_t)c * PK + pos];
          unsigned flat = (unsigned)(c * PK + pos);
          cand[c * MDET + base] =
              (tkey & 0xFFFFFFFF00000000ull) | (u64)(0xFFFFFFFFu - flat);
        }
        base++;
      }
    }
  }
  __syncthreads();

  // histogram scores into bins
  for (int t = tid; t < NC * MDET; t += 1024) {
    u64 k = cand[t];
    if (k) atomicAdd(&hist[(int)(((unsigned)(k >> 32) - SB) >> 3)], 1u);
  }
  __syncthreads();

  // per-thread chunk sums + block suffix scan
  const int CH = (NB + 1023) >> 10;
  int clo = tid * CH, chi = min(clo + CH, NB);
  unsigned s = 0;
  for (int b = clo; b < chi; ++b) s += hist[b];
  sscan[tid] = s;
  __syncthreads();
  for (int d = 1; d < 1024; d <<= 1) {
    unsigned v = sscan[tid];
    unsigned add = (tid + d < 1024) ? sscan[tid + d] : 0u;
    __syncthreads();
    sscan[tid] = v + add;
    __syncthreads();
  }
  unsigned suff = sscan[tid];
  unsigned suffn = (tid < 1023) ? sscan[tid + 1] : 0u;
  if (tid == 0 && sscan[0] < MDET) { s_B = 0; s_gc = (int)sscan[0]; }
  if (suff >= MDET && (tid == 1023 || suffn < MDET)) {
    unsigned after = suffn;          // count in bins above this chunk
    int B = clo;
    for (int b = chi - 1; b >= clo; --b) {
      after += hist[b];
      if (after >= MDET) { B = b; break; }
    }
    s_B = B; s_gc = (int)after;
  }
  __syncthreads();
  const int B = s_B, gc = s_gc;

  u64* sel;
  if (gc <= 1024) {
    for (int t = tid; t < 1024; t += 1024) sbuf[t] = 0ULL;
    __syncthreads();
    for (int t = tid; t < NC * MDET; t += 1024) {
      u64 k = cand[t];
      if (k && (int)(((unsigned)(k >> 32) - SB) >> 3) >= B)
        sbuf[atomicAdd(&s_gcnt, 1)] = k;
    }
    __syncthreads();
    bitonic_desc(sbuf, 1024, tid, 1024);
    sel = sbuf;
  } else {
    // pathological tie-pileup: full sort fallback (hist/sbuf regions dead now)
    for (int t = tid; t < 16384; t += 1024)
      if (t >= NC * MDET) buf[t] = 0ULL;
    __syncthreads();
    bitonic_desc(buf, 16384, tid, 1024);
    sel = buf;
  }

  // gather top-100 outputs
  if (tid < MDET) {
    u64 key = sel[tid];
    bool ok = (key != 0ULL);
    float b0 = -1.f, b1 = -1.f, b2 = -1.f, b3 = -1.f;
    float r0 = -1.f, r1 = -1.f, r2 = -1.f;
    float t0 = -1.f, t1 = -1.f, t2 = -1.f;
    float sc = -1.f, lab = -1.f;
    if (ok) {
      float score = __uint_as_float((unsigned)(key >> 32));
      unsigned flat = 0xFFFFFFFFu - (unsigned)(key & 0xFFFFFFFFull);
      int c = flat >> 10, pos = flat & 1023;
      u64 tkey = topk[(size_t)c * PK + pos];
      unsigned aidx = 0xFFFFFFFFu - (unsigned)(tkey & 0xFFFFFFFFull);
      float4 bb = boxes[aidx];
      b0 = bb.x; b1 = bb.y; b2 = bb.z; b3 = bb.w;
      sc = score; lab = (float)c;
      r0 = rot[aidx*3+0]; r1 = rot[aidx*3+1]; r2 = rot[aidx*3+2];
      t0 = trn[aidx*3+0]; t1 = trn[aidx*3+1]; t2 = trn[aidx*3+2];
    }
    out[tid*4+0] = b0; out[tid*4+1] = b1; out[tid*4+2] = b2; out[tid*4+3] = b3;
    out[400 + tid] = sc;
    out[500 + tid] = lab;
    out[600 + tid*3+0] = r0; out[600 + tid*3+1] = r1; out[600 + tid*3+2] = r2;
    out[900 + tid*3+0] = t0; out[900 + tid*3+1] = t1; out[900 + tid*3+2] = t2;
  }
}

extern "C" void kernel_launch(void* const* d_in, const int* in_sizes, int n_in,
                              void* d_out, int out_size, void* d_ws, size_t ws_size,
                              hipStream_t stream) {
  const float* anchors        = (const float*)d_in[0];
  const float* regression     = (const float*)d_in[1];
  const float* classification = (const float*)d_in[2];
  const float* rotation       = (const float*)d_in[3];
  const float* tanch          = (const float*)d_in[4];
  const float* tdelta         = (const float*)d_in[5];
  float* out = (float*)d_out;

  char* ws = (char*)d_ws;
  size_t off = 0;
  auto alloc = [&](size_t bytes) -> void* {
    void* p = ws + off;
    off += (bytes + 255) & ~(size_t)255;
    return p;
  };
  float*    boxes  = (float*)alloc((size_t)NA * 4 * 4);
  float*    trn    = (float*)alloc((size_t)NA * 3 * 4);
  int*      counts = (int*)alloc(NC * CPAD * 4);
  int*      mcount = (int*)alloc(NC * 4);
  u64*      cand   = (u64*)alloc((size_t)NC * CMAX * 8);
  u64*      topk   = (u64*)alloc((size_t)NC * PK * 8);
  unsigned* keep   = (unsigned*)alloc(NC * 32 * 4);

  hipMemsetAsync(counts, 0, NC * CPAD * 4, stream);

  k_decode<<<(NA + 255) / 256, 256, 0, stream>>>(
      (const float4*)anchors, (const float4*)regression, tanch, tdelta,
      (float4*)boxes, trn);
  k_collect<<<2048, 256, 0, stream>>>((const float4*)classification, counts, cand);
  k_sortclass<<<NC, 1024, 0, stream>>>(counts, cand, topk, mcount);

  hipFuncSetAttribute(reinterpret_cast<const void*>(k_nms),
                      hipFuncAttributeMaxDynamicSharedMemorySize, 131072);
  k_nms<<<NC, 1024, 131072, stream>>>(topk, mcount, (const float4*)boxes, keep);

  hipFuncSetAttribute(reinterpret_cast<const void*>(k_final),
                      hipFuncAttributeMaxDynamicSharedMemorySize, 131072);
  k_final<<<1, 1024, 131072, stream>>>(topk, keep, (const float4*)boxes, rotation, trn, out);
}

// Round 4
// 218.594 us; speedup vs baseline: 3.6020x; 1.1562x over previous
//
#include <hip/hip_runtime.h>

#define NA 150381
#define NC 90
#define PK 1024
#define CMAX 4096
#define MDET 100
#define STHR 0.996f
#define NTHR 0.5f
#define IMGF 896.0f
#define CPAD 32  // counts padded: one 128B cacheline per class

typedef unsigned long long u64;

// ---------------- decode boxes + translation ----------------
__global__ void k_decode(const float4* __restrict__ anc, const float4* __restrict__ reg,
                         const float* __restrict__ ta, const float* __restrict__ td,
                         float4* __restrict__ boxes, float* __restrict__ trn) {
  int i = blockIdx.x * blockDim.x + threadIdx.x;
  if (i >= NA) return;
  float4 a = anc[i];
  float4 r = reg[i];
  float cxa = (a.x + a.z) * 0.5f, cya = (a.y + a.w) * 0.5f;
  float wa = a.z - a.x, ha = a.w - a.y;
  float w = expf(r.w) * wa, h = expf(r.z) * ha;
  float cy = r.x * ha + cya, cx = r.y * wa + cxa;
  float4 b;
  b.x = fminf(fmaxf(cx - w * 0.5f, 0.f), IMGF);
  b.y = fminf(fmaxf(cy - h * 0.5f, 0.f), IMGF);
  b.z = fminf(fmaxf(cx + w * 0.5f, 0.f), IMGF);
  b.w = fminf(fmaxf(cy + h * 0.5f, 0.f), IMGF);
  boxes[i] = b;
  float st = ta[i*3+2];
  trn[i*3+0] = ta[i*3+0] + td[i*3+0] * st;
  trn[i*3+1] = ta[i*3+1] + td[i*3+1] * st;
  trn[i*3+2] = td[i*3+2];
}

// ---------------- threshold filter into per-class candidate lists ----------------
__global__ void k_collect(const float4* __restrict__ cls4, int* __restrict__ counts,
                          u64* __restrict__ cand) {
  const int total = NA * NC;
  const int nv4 = total >> 2;
  const int stride = gridDim.x * blockDim.x;
  for (int q = blockIdx.x * blockDim.x + threadIdx.x; q < nv4; q += stride) {
    float4 v4 = cls4[q];
    float vv[4] = {v4.x, v4.y, v4.z, v4.w};
    #pragma unroll
    for (int e = 0; e < 4; ++e) {
      float v = vv[e];
      if (v > STHR) {
        int f = q * 4 + e;
        int c = f % NC;
        int i = f / NC;
        int pos = atomicAdd(&counts[c * CPAD], 1);
        if (pos < CMAX)
          cand[(size_t)c * CMAX + pos] =
              ((u64)__float_as_uint(v) << 32) | (u64)(0xFFFFFFFFu - (unsigned)i);
      }
    }
  }
  int g = blockIdx.x * blockDim.x + threadIdx.x;
  if (g < total - nv4 * 4) {
    int f = nv4 * 4 + g;
    float v = ((const float*)cls4)[f];
    if (v > STHR) {
      int c = f % NC;
      int i = f / NC;
      int pos = atomicAdd(&counts[c * CPAD], 1);
      if (pos < CMAX)
        cand[(size_t)c * CMAX + pos] =
            ((u64)__float_as_uint(v) << 32) | (u64)(0xFFFFFFFFu - (unsigned)i);
    }
  }
}

__device__ __forceinline__ void bitonic_desc(u64* a, int n, int tid, int nth) {
  for (int k = 2; k <= n; k <<= 1) {
    for (int j = k >> 1; j > 0; j >>= 1) {
      __syncthreads();
      for (int i = tid; i < n; i += nth) {
        int ixj = i ^ j;
        if (ixj > i) {
          u64 x = a[i], y = a[ixj];
          if (((i & k) == 0) ? (x < y) : (x > y)) { a[i] = y; a[ixj] = x; }
        }
      }
    }
  }
  __syncthreads();
}

// ---------------- fused per-class: sort -> topk -> sup matrix -> kept-only scan ----
// sup layout swizzled: word w of row i stored at column (w+i)&31 -> conflict-free
// reads AND writes. Lower-triangle words (w < i>>5) are never consulted by the
// kept-only scan (todo bits below the current minimum are already clear), so
// they are left unwritten.
__global__ __launch_bounds__(1024) void k_sortnms(const int* __restrict__ counts,
                                                  const u64* __restrict__ cand,
                                                  const float4* __restrict__ boxes,
                                                  u64* __restrict__ topk,
                                                  unsigned* __restrict__ keep_out) {
  extern __shared__ u64 dyn[];            // 131072 B: sort buf, then sup matrix
  u64* sbuf = dyn;                        // up to CMAX u64 = 32 KB
  unsigned* sup = (unsigned*)dyn;         // [PK][32] swizzled = 128 KB
  __shared__ float bx1[PK], by1[PK], bx2[PK], by2[PK], ar[PK];
  const int c = blockIdx.x, tid = threadIdx.x;

  int M = min(counts[c * CPAD], CMAX);
  int NS = PK;
  while (NS < M) NS <<= 1;
  for (int k = tid; k < NS; k += 1024)
    sbuf[k] = (k < M) ? cand[(size_t)c * CMAX + k] : 0ULL;
  bitonic_desc(sbuf, NS, tid, 1024);

  const int Mk = min(M, PK);
  // topk to global (k_final gathers through it); boxes to static LDS
  for (int k = tid; k < PK; k += 1024) topk[(size_t)c * PK + k] = sbuf[k];
  for (int t = tid; t < Mk; t += 1024) {
    u64 key = sbuf[t];
    unsigned aidx = 0xFFFFFFFFu - (unsigned)(key & 0xFFFFFFFFull);
    float4 b = boxes[aidx];
    bx1[t] = b.x; by1[t] = b.y; bx2[t] = b.z; by2[t] = b.w;
    ar[t] = (b.z - b.x) * (b.w - b.y);
  }
  __syncthreads();  // sbuf dead; sup may now overwrite it

  if (tid < Mk) {
    float x1 = bx1[tid], y1 = by1[tid], x2 = bx2[tid], y2 = by2[tid], ai = ar[tid];
    const int nw = (Mk + 31) >> 5;
    for (int w = tid >> 5; w < nw; ++w) {
      unsigned word = 0;
      int jb = w << 5;
      int jend = min(Mk - jb, 32);
      for (int b = 0; b < jend; ++b) {
        int j = jb + b;
        if (j > tid) {
          float ix1 = fmaxf(x1, bx1[j]), iy1 = fmaxf(y1, by1[j]);
          float ix2 = fminf(x2, bx2[j]), iy2 = fminf(y2, by2[j]);
          float iw = fmaxf(ix2 - ix1, 0.f), ih = fmaxf(iy2 - iy1, 0.f);
          float inter = iw * ih;
          float uni = ai + ar[j] - inter;
          if (inter / fmaxf(uni, 1e-9f) > NTHR) word |= 1u << b;
        }
      }
      sup[(tid << 5) + ((w + tid) & 31)] = word;
    }
  }
  __syncthreads();

  // kept-only greedy scan: one wave, iterations == number of KEPT boxes.
  if (tid < 64) {
    unsigned todo = 0;
    if (tid < 32) {
      int lo = tid << 5;
      todo = (Mk <= lo) ? 0u : ((Mk - lo >= 32) ? 0xFFFFFFFFu : ((1u << (Mk - lo)) - 1u));
    }
    unsigned keep_acc = 0;
    while (true) {
      u64 bal = __ballot(todo != 0u);
      if (bal == 0ull) break;
      int L = __ffsll(bal) - 1;                                  // word holding next survivor
      unsigned ow = (unsigned)__builtin_amdgcn_readlane((int)todo, L);
      int b = __ffs(ow) - 1;
      int i = (L << 5) + b;                                      // next kept index
      unsigned srow = sup[(i << 5) + ((tid + i) & 31)];          // row i, word tid (swizzled)
      if (tid == L) { keep_acc |= 1u << b; todo &= ~(1u << b); }
      todo &= ~srow;
    }
    if (tid < 32) keep_out[(c << 5) + tid] = keep_acc;
  }
}

// ---------------- global top-100 via radix-select + small sort + gather ----------------
__global__ __launch_bounds__(1024) void k_final(const u64* __restrict__ topk,
                                                const unsigned* __restrict__ keep,
                                                const float4* __restrict__ boxes,
                                                const float* __restrict__ rot,
                                                const float* __restrict__ trn,
                                                float* __restrict__ out) {
  extern __shared__ u64 buf[];                       // 16384 u64 = 131072 B
  u64* cand = buf;                                   // slots [0, 9000)
  unsigned* hist = (unsigned*)(buf + 9216);          // 8448 u32 bins
  u64* sbuf = (u64*)((char*)buf + 9216*8 + 8448*4);  // 1024 u64
  __shared__ unsigned wsum[16], wsuf[16];
  __shared__ int s_B, s_gc, s_gcnt;

  const int tid = threadIdx.x;
  const int wave = tid >> 6;
  const int lane = tid & 63;
  const unsigned SB = __float_as_uint(STHR);
  const int NB = (int)((0x3F800000u - SB) >> 3) + 1;  // ~8390 bins

  for (int t = tid; t < NC * MDET; t += 1024) cand[t] = 0ULL;
  for (int t = tid; t < NB; t += 1024) hist[t] = 0u;
  if (tid == 0) s_gcnt = 0;
  __syncthreads();

  // collect first <=100 kept per class (positions ascending == scores descending)
  for (int c = wave; c < NC; c += 16) {
    if (lane < 32) {
      unsigned w = keep[c * 32 + lane];
      int pc = __popc(w);
      int scan = pc;
      for (int d = 1; d < 32; d <<= 1) {
        int v = __shfl_up(scan, d);
        if (lane >= d) scan += v;
      }
      int base = scan - pc;
      unsigned ww = w;
      while (ww) {
        int b = __ffs(ww) - 1;
        ww &= ww - 1u;
        if (base < MDET) {
          int pos = lane * 32 + b;
          u64 tkey = topk[(size_t)c * PK + pos];
          unsigned flat = (unsigned)(c * PK + pos);
          cand[c * MDET + base] =
              (tkey & 0xFFFFFFFF00000000ull) | (u64)(0xFFFFFFFFu - flat);
        }
        base++;
      }
    }
  }
  __syncthreads();

  // histogram scores into bins
  for (int t = tid; t < NC * MDET; t += 1024) {
    u64 k = cand[t];
    if (k) atomicAdd(&hist[(int)(((unsigned)(k >> 32) - SB) >> 3)], 1u);
  }
  __syncthreads();

  // hierarchical suffix scan: chunk sums -> intra-wave shfl suffix -> 16-wave combine
  const int CH = (NB + 1023) >> 10;
  int clo = tid * CH, chi = min(clo + CH, NB);
  unsigned s = 0;
  for (int bb = clo; bb < chi; ++bb) s += hist[bb];
  unsigned ss = s;
  for (int d = 1; d < 64; d <<= 1) {
    unsigned v = __shfl_down(ss, d);
    if (lane + d < 64) ss += v;
  }
  if (lane == 0) wsum[wave] = ss;   // wave-total
  __syncthreads();
  if (tid < 16) {
    unsigned t = wsum[tid];
    for (int d = 1; d < 16; d <<= 1) {
      unsigned v = __shfl_down(t, d);
      if (tid + d < 16) t += v;
    }
    wsuf[tid] = t;                  // suffix over waves >= tid
  }
  __syncthreads();
  unsigned suff = ss + ((wave < 15) ? wsuf[wave + 1] : 0u);  // suffix incl. own chunk
  unsigned suffn = suff - s;                                  // suffix from next chunk
  if (tid == 0 && wsuf[0] < MDET) { s_B = 0; s_gc = (int)wsuf[0]; }
  if (suff >= MDET && suffn < MDET) {
    unsigned after = suffn;
    int Bf = clo;
    for (int bb = chi - 1; bb >= clo; --bb) {
      after += hist[bb];
      if (after >= MDET) { Bf = bb; break; }
    }
    s_B = Bf; s_gc = (int)after;
  }
  __syncthreads();
  const int B = s_B, gc = s_gc;

  u64* sel;
  if (gc <= 1024) {
    int NSf = 128;
    while (NSf < gc) NSf <<= 1;
    for (int t = tid; t < NSf; t += 1024) sbuf[t] = 0ULL;
    __syncthreads();
    for (int t = tid; t < NC * MDET; t += 1024) {
      u64 k = cand[t];
      if (k && (int)(((unsigned)(k >> 32) - SB) >> 3) >= B)
        sbuf[atomicAdd(&s_gcnt, 1)] = k;
    }
    __syncthreads();
    bitonic_desc(sbuf, NSf, tid, 1024);
    sel = sbuf;
  } else {
    // pathological tie-pileup: full sort fallback
    for (int t = tid; t < 16384; t += 1024)
      if (t >= NC * MDET) buf[t] = 0ULL;
    __syncthreads();
    bitonic_desc(buf, 16384, tid, 1024);
    sel = buf;
  }

  // gather top-100 outputs
  if (tid < MDET) {
    u64 key = sel[tid];
    bool ok = (key != 0ULL);
    float b0 = -1.f, b1 = -1.f, b2 = -1.f, b3 = -1.f;
    float r0 = -1.f, r1 = -1.f, r2 = -1.f;
    float t0 = -1.f, t1 = -1.f, t2 = -1.f;
    float sc = -1.f, lab = -1.f;
    if (ok) {
      float score = __uint_as_float((unsigned)(key >> 32));
      unsigned flat = 0xFFFFFFFFu - (unsigned)(key & 0xFFFFFFFFull);
      int c = flat >> 10, pos = flat & 1023;
      u64 tkey = topk[(size_t)c * PK + pos];
      unsigned aidx = 0xFFFFFFFFu - (unsigned)(tkey & 0xFFFFFFFFull);
      float4 bb = boxes[aidx];
      b0 = bb.x; b1 = bb.y; b2 = bb.z; b3 = bb.w;
      sc = score; lab = (float)c;
      r0 = rot[aidx*3+0]; r1 = rot[aidx*3+1]; r2 = rot[aidx*3+2];
      t0 = trn[aidx*3+0]; t1 = trn[aidx*3+1]; t2 = trn[aidx*3+2];
    }
    out[tid*4+0] = b0; out[tid*4+1] = b1; out[tid*4+2] = b2; out[tid*4+3] = b3;
    out[400 + tid] = sc;
    out[500 + tid] = lab;
    out[600 + tid*3+0] = r0; out[600 + tid*3+1] = r1; out[600 + tid*3+2] = r2;
    out[900 + tid*3+0] = t0; out[900 + tid*3+1] = t1; out[900 + tid*3+2] = t2;
  }
}

extern "C" void kernel_launch(void* const* d_in, const int* in_sizes, int n_in,
                              void* d_out, int out_size, void* d_ws, size_t ws_size,
                              hipStream_t stream) {
  const float* anchors        = (const float*)d_in[0];
  const float* regression     = (const float*)d_in[1];
  const float* classification = (const float*)d_in[2];
  const float* rotation       = (const float*)d_in[3];
  const float* tanch          = (const float*)d_in[4];
  const float* tdelta         = (const float*)d_in[5];
  float* out = (float*)d_out;

  char* ws = (char*)d_ws;
  size_t off = 0;
  auto alloc = [&](size_t bytes) -> void* {
    void* p = ws + off;
    off += (bytes + 255) & ~(size_t)255;
    return p;
  };
  float*    boxes  = (float*)alloc((size_t)NA * 4 * 4);
  float*    trn    = (float*)alloc((size_t)NA * 3 * 4);
  int*      counts = (int*)alloc(NC * CPAD * 4);
  u64*      cand   = (u64*)alloc((size_t)NC * CMAX * 8);
  u64*      topk   = (u64*)alloc((size_t)NC * PK * 8);
  unsigned* keep   = (unsigned*)alloc(NC * 32 * 4);

  hipMemsetAsync(counts, 0, NC * CPAD * 4, stream);

  k_decode<<<(NA + 255) / 256, 256, 0, stream>>>(
      (const float4*)anchors, (const float4*)regression, tanch, tdelta,
      (float4*)boxes, trn);
  k_collect<<<2048, 256, 0, stream>>>((const float4*)classification, counts, cand);

  hipFuncSetAttribute(reinterpret_cast<const void*>(k_sortnms),
                      hipFuncAttributeMaxDynamicSharedMemorySize, 131072);
  k_sortnms<<<NC, 1024, 131072, stream>>>(counts, cand, (const float4*)boxes, topk, keep);

  hipFuncSetAttribute(reinterpret_cast<const void*>(k_final),
                      hipFuncAttributeMaxDynamicSharedMemorySize, 131072);
  k_final<<<1, 1024, 131072, stream>>>(topk, keep, (const float4*)boxes, rotation, trn, out);
}

// Round 5
// 161.415 us; speedup vs baseline: 4.8779x; 1.3542x over previous
//
#include <hip/hip_runtime.h>

#define NA 150381
#define NC 90
#define PK 1024
#define CMAX 4096
#define MDET 100
#define STHR 0.996f
#define NTHR 0.5f
#define IMGF 896.0f
#define CPAD 32   // counts padded: one 128B cacheline per class
#define BCH 128   // sup-matrix build chunk (rows)

typedef unsigned long long u64;

// ---------------- decode boxes + translation ----------------
__global__ void k_decode(const float4* __restrict__ anc, const float4* __restrict__ reg,
                         const float* __restrict__ ta, const float* __restrict__ td,
                         float4* __restrict__ boxes, float* __restrict__ trn) {
  int i = blockIdx.x * blockDim.x + threadIdx.x;
  if (i >= NA) return;
  float4 a = anc[i];
  float4 r = reg[i];
  float cxa = (a.x + a.z) * 0.5f, cya = (a.y + a.w) * 0.5f;
  float wa = a.z - a.x, ha = a.w - a.y;
  float w = expf(r.w) * wa, h = expf(r.z) * ha;
  float cy = r.x * ha + cya, cx = r.y * wa + cxa;
  float4 b;
  b.x = fminf(fmaxf(cx - w * 0.5f, 0.f), IMGF);
  b.y = fminf(fmaxf(cy - h * 0.5f, 0.f), IMGF);
  b.z = fminf(fmaxf(cx + w * 0.5f, 0.f), IMGF);
  b.w = fminf(fmaxf(cy + h * 0.5f, 0.f), IMGF);
  boxes[i] = b;
  float st = ta[i*3+2];
  trn[i*3+0] = ta[i*3+0] + td[i*3+0] * st;
  trn[i*3+1] = ta[i*3+1] + td[i*3+1] * st;
  trn[i*3+2] = td[i*3+2];
}

// ---------------- threshold filter into per-class candidate lists ----------------
__global__ void k_collect(const float4* __restrict__ cls4, int* __restrict__ counts,
                          u64* __restrict__ cand) {
  const int total = NA * NC;
  const int nv4 = total >> 2;
  const int stride = gridDim.x * blockDim.x;
  for (int q = blockIdx.x * blockDim.x + threadIdx.x; q < nv4; q += stride) {
    float4 v4 = cls4[q];
    float vv[4] = {v4.x, v4.y, v4.z, v4.w};
    #pragma unroll
    for (int e = 0; e < 4; ++e) {
      float v = vv[e];
      if (v > STHR) {
        int f = q * 4 + e;
        int c = f % NC;
        int i = f / NC;
        int pos = atomicAdd(&counts[c * CPAD], 1);
        if (pos < CMAX)
          cand[(size_t)c * CMAX + pos] =
              ((u64)__float_as_uint(v) << 32) | (u64)(0xFFFFFFFFu - (unsigned)i);
      }
    }
  }
  int g = blockIdx.x * blockDim.x + threadIdx.x;
  if (g < total - nv4 * 4) {
    int f = nv4 * 4 + g;
    float v = ((const float*)cls4)[f];
    if (v > STHR) {
      int c = f % NC;
      int i = f / NC;
      int pos = atomicAdd(&counts[c * CPAD], 1);
      if (pos < CMAX)
        cand[(size_t)c * CMAX + pos] =
            ((u64)__float_as_uint(v) << 32) | (u64)(0xFFFFFFFFu - (unsigned)i);
    }
  }
}

__device__ __forceinline__ void bitonic_desc(u64* a, int n, int tid, int nth) {
  for (int k = 2; k <= n; k <<= 1) {
    for (int j = k >> 1; j > 0; j >>= 1) {
      __syncthreads();
      for (int i = tid; i < n; i += nth) {
        int ixj = i ^ j;
        if (ixj > i) {
          u64 x = a[i], y = a[ixj];
          if (((i & k) == 0) ? (x < y) : (x > y)) { a[i] = y; a[ixj] = x; }
        }
      }
    }
  }
  __syncthreads();
}

// ---------------- fused per-class: sort -> topk -> lazy sup chunks + capped scan ----
// sup row layout swizzled: word w of row i at column (w+i)&31 (conflict-free).
// Lower-triangle words unwritten (never consulted: todo bits below current
// survivor are already clear). Scan visits survivors in strictly increasing
// rank and stops after MDET kept (k_final consumes at most MDET per class).
__global__ __launch_bounds__(1024) void k_sortnms(const int* __restrict__ counts,
                                                  const u64* __restrict__ cand,
                                                  const float4* __restrict__ boxes,
                                                  u64* __restrict__ topk,
                                                  unsigned* __restrict__ keep_out) {
  extern __shared__ u64 dyn[];            // 131072 B: sort spill buf, then sup
  u64* sbuf = dyn;
  unsigned* sup = (unsigned*)dyn;         // [PK][32] swizzled = 128 KB
  __shared__ float bx1[PK], by1[PK], bx2[PK], by2[PK], ar[PK];
  __shared__ int s_done;
  const int c = blockIdx.x, tid = threadIdx.x;

  const int M = min(counts[c * CPAD], CMAX);
  if (tid == 0) s_done = 0;

  // ---- sort: element-per-thread bitonic; shfl for j<64, LDS for j>=64 ----
  u64 v;
  if (M <= PK) {
    v = (tid < M) ? cand[(size_t)c * CMAX + tid] : 0ULL;
    for (int k = 2; k <= PK; k <<= 1) {
      for (int j = k >> 1; j > 0; j >>= 1) {
        u64 p;
        if (j >= 64) {
          __syncthreads();
          sbuf[tid] = v;
          __syncthreads();
          p = sbuf[tid ^ j];
        } else {
          p = __shfl_xor(v, j, 64);
        }
        u64 mx = (v >= p) ? v : p, mn = (v >= p) ? p : v;
        bool takeMax = (((tid & k) == 0) != ((tid & j) != 0));
        v = takeMax ? mx : mn;
      }
    }
  } else {
    // rare fallback: full LDS bitonic over next-pow2(M), take top PK
    int NS = PK;
    while (NS < M) NS <<= 1;
    for (int k = tid; k < NS; k += 1024)
      sbuf[k] = (k < M) ? cand[(size_t)c * CMAX + k] : 0ULL;
    bitonic_desc(sbuf, NS, tid, 1024);
    v = sbuf[tid];
  }

  const int Mk = min(M, PK);
  if (tid < Mk) {
    topk[(size_t)c * PK + tid] = v;
    unsigned aidx = 0xFFFFFFFFu - (unsigned)(v & 0xFFFFFFFFull);
    float4 b = boxes[aidx];
    bx1[tid] = b.x; by1[tid] = b.y; bx2[tid] = b.z; by2[tid] = b.w;
    ar[tid] = (b.z - b.x) * (b.w - b.y);
  }
  __syncthreads();  // sbuf dead; sup may now overwrite dyn

  // ---- scan state (wave 0 registers) ----
  unsigned todo = 0, keep_acc = 0;
  if (tid < 32) {
    int lo = tid << 5;
    todo = (Mk <= lo) ? 0u : ((Mk - lo >= 32) ? 0xFFFFFFFFu : ((1u << (Mk - lo)) - 1u));
  }
  int kept_total = 0;

  const int NCH = (Mk + BCH - 1) / BCH;
  for (int ch = 0; ch < NCH; ++ch) {
    // ---- build chunk rows [ch*BCH, ch*BCH+BCH): 8 threads per row ----
    {
      int r = ch * BCH + (tid >> 3);
      if (r < Mk) {
        const int s = tid & 7;
        const float x1 = bx1[r], y1 = by1[r], x2 = bx2[r], y2 = by2[r], ai = ar[r];
        const int nw = (Mk + 31) >> 5;
        const int w0 = r >> 5;
        for (int w = s; w < nw; w += 8) {
          if (w < w0) continue;          // lower-triangle word: never consulted
          unsigned word = 0;
          const int jb = w << 5;
          const int rot = s << 2;        // bank-rotated column order
          #pragma unroll 4
          for (int bb = 0; bb < 32; ++bb) {
            int b = (bb + rot) & 31;
            int j = jb + b;
            if (j > r && j < Mk) {
              float ix1 = fmaxf(x1, bx1[j]), iy1 = fmaxf(y1, by1[j]);
              float ix2 = fminf(x2, bx2[j]), iy2 = fminf(y2, by2[j]);
              float iw = fmaxf(ix2 - ix1, 0.f), ih = fmaxf(iy2 - iy1, 0.f);
              float inter = iw * ih;
              float uni = ai + ar[j] - inter;
              if (inter / fmaxf(uni, 1e-9f) > NTHR) word |= 1u << b;
            }
          }
          sup[(r << 5) + ((w + r) & 31)] = word;
        }
      }
    }
    __syncthreads();

    // ---- kept-only greedy scan within built region, capped at MDET kept ----
    if (tid < 64) {
      const int hi = min((ch + 1) * BCH, Mk);
      while (kept_total < MDET) {
        u64 bal = __ballot(todo != 0u);
        if (bal == 0ull) { if (tid == 0) s_done = 1; break; }
        int L = __ffsll(bal) - 1;
        unsigned ow = (unsigned)__builtin_amdgcn_readlane((int)todo, L);
        int b = __ffs(ow) - 1;
        int i = (L << 5) + b;            // next survivor (strictly increasing)
        if (i >= hi) break;              // need next chunk built first
        unsigned srow = sup[(i << 5) + ((tid + i) & 31)];
        if (tid == L) { keep_acc |= 1u << b; todo &= ~(1u << b); }
        todo &= ~srow;
        if (++kept_total >= MDET) { if (tid == 0) s_done = 1; }
      }
    }
    __syncthreads();
    if (s_done) break;
  }

  if (tid < 32) keep_out[(c << 5) + tid] = keep_acc;
}

// ---------------- global top-100 via radix-select + small sort + gather ----------------
__global__ __launch_bounds__(1024) void k_final(const u64* __restrict__ topk,
                                                const unsigned* __restrict__ keep,
                                                const float4* __restrict__ boxes,
                                                const float* __restrict__ rot,
                                                const float* __restrict__ trn,
                                                float* __restrict__ out) {
  extern __shared__ u64 buf[];                       // 16384 u64 = 131072 B
  u64* cand = buf;                                   // slots [0, 9000)
  unsigned* hist = (unsigned*)(buf + 9216);          // 8448 u32 bins
  u64* sbuf = (u64*)((char*)buf + 9216*8 + 8448*4);  // 1024 u64
  __shared__ unsigned wsum[16], wsuf[16];
  __shared__ int s_B, s_gc, s_gcnt;

  const int tid = threadIdx.x;
  const int wave = tid >> 6;
  const int lane = tid & 63;
  const unsigned SB = __float_as_uint(STHR);
  const int NB = (int)((0x3F800000u - SB) >> 3) + 1;  // ~8390 bins

  for (int t = tid; t < NC * MDET; t += 1024) cand[t] = 0ULL;
  for (int t = tid; t < NB; t += 1024) hist[t] = 0u;
  if (tid == 0) s_gcnt = 0;
  __syncthreads();

  // collect first <=100 kept per class (positions ascending == scores descending)
  for (int c = wave; c < NC; c += 16) {
    if (lane < 32) {
      unsigned w = keep[c * 32 + lane];
      int pc = __popc(w);
      int scan = pc;
      for (int d = 1; d < 32; d <<= 1) {
        int v = __shfl_up(scan, d);
        if (lane >= d) scan += v;
      }
      int base = scan - pc;
      unsigned ww = w;
      while (ww && base < MDET) {
        int b = __ffs(ww) - 1;
        ww &= ww - 1u;
        int pos = lane * 32 + b;
        u64 tkey = topk[(size_t)c * PK + pos];
        unsigned flat = (unsigned)(c * PK + pos);
        cand[c * MDET + base] =
            (tkey & 0xFFFFFFFF00000000ull) | (u64)(0xFFFFFFFFu - flat);
        base++;
      }
    }
  }
  __syncthreads();

  // histogram scores into bins
  for (int t = tid; t < NC * MDET; t += 1024) {
    u64 k = cand[t];
    if (k) atomicAdd(&hist[(int)(((unsigned)(k >> 32) - SB) >> 3)], 1u);
  }
  __syncthreads();

  // hierarchical suffix scan: chunk sums -> intra-wave shfl suffix -> 16-wave combine
  const int CH = (NB + 1023) >> 10;
  int clo = tid * CH, chi = min(clo + CH, NB);
  unsigned s = 0;
  for (int bb = clo; bb < chi; ++bb) s += hist[bb];
  unsigned ss = s;
  for (int d = 1; d < 64; d <<= 1) {
    unsigned v = __shfl_down(ss, d);
    if (lane + d < 64) ss += v;
  }
  if (lane == 0) wsum[wave] = ss;
  __syncthreads();
  if (tid < 16) {
    unsigned t = wsum[tid];
    for (int d = 1; d < 16; d <<= 1) {
      unsigned v = __shfl_down(t, d);
      if (tid + d < 16) t += v;
    }
    wsuf[tid] = t;
  }
  __syncthreads();
  unsigned suff = ss + ((wave < 15) ? wsuf[wave + 1] : 0u);
  unsigned suffn = suff - s;
  if (tid == 0 && wsuf[0] < MDET) { s_B = 0; s_gc = (int)wsuf[0]; }
  if (suff >= MDET && suffn < MDET) {
    unsigned after = suffn;
    int Bf = clo;
    for (int bb = chi - 1; bb >= clo; --bb) {
      after += hist[bb];
      if (after >= MDET) { Bf = bb; break; }
    }
    s_B = Bf; s_gc = (int)after;
  }
  __syncthreads();
  const int B = s_B, gc = s_gc;

  u64* sel;
  if (gc <= 1024) {
    int NSf = 128;
    while (NSf < gc) NSf <<= 1;
    for (int t = tid; t < NSf; t += 1024) sbuf[t] = 0ULL;
    __syncthreads();
    for (int t = tid; t < NC * MDET; t += 1024) {
      u64 k = cand[t];
      if (k && (int)(((unsigned)(k >> 32) - SB) >> 3) >= B)
        sbuf[atomicAdd(&s_gcnt, 1)] = k;
    }
    __syncthreads();
    bitonic_desc(sbuf, NSf, tid, 1024);
    sel = sbuf;
  } else {
    for (int t = tid; t < 16384; t += 1024)
      if (t >= NC * MDET) buf[t] = 0ULL;
    __syncthreads();
    bitonic_desc(buf, 16384, tid, 1024);
    sel = buf;
  }

  // gather top-100 outputs
  if (tid < MDET) {
    u64 key = sel[tid];
    bool ok = (key != 0ULL);
    float b0 = -1.f, b1 = -1.f, b2 = -1.f, b3 = -1.f;
    float r0 = -1.f, r1 = -1.f, r2 = -1.f;
    float t0 = -1.f, t1 = -1.f, t2 = -1.f;
    float sc = -1.f, lab = -1.f;
    if (ok) {
      float score = __uint_as_float((unsigned)(key >> 32));
      unsigned flat = 0xFFFFFFFFu - (unsigned)(key & 0xFFFFFFFFull);
      int c = flat >> 10, pos = flat & 1023;
      u64 tkey = topk[(size_t)c * PK + pos];
      unsigned aidx = 0xFFFFFFFFu - (unsigned)(tkey & 0xFFFFFFFFull);
      float4 bb = boxes[aidx];
      b0 = bb.x; b1 = bb.y; b2 = bb.z; b3 = bb.w;
      sc = score; lab = (float)c;
      r0 = rot[aidx*3+0]; r1 = rot[aidx*3+1]; r2 = rot[aidx*3+2];
      t0 = trn[aidx*3+0]; t1 = trn[aidx*3+1]; t2 = trn[aidx*3+2];
    }
    out[tid*4+0] = b0; out[tid*4+1] = b1; out[tid*4+2] = b2; out[tid*4+3] = b3;
    out[400 + tid] = sc;
    out[500 + tid] = lab;
    out[600 + tid*3+0] = r0; out[600 + tid*3+1] = r1; out[600 + tid*3+2] = r2;
    out[900 + tid*3+0] = t0; out[900 + tid*3+1] = t1; out[900 + tid*3+2] = t2;
  }
}

extern "C" void kernel_launch(void* const* d_in, const int* in_sizes, int n_in,
                              void* d_out, int out_size, void* d_ws, size_t ws_size,
                              hipStream_t stream) {
  const float* anchors        = (const float*)d_in[0];
  const float* regression     = (const float*)d_in[1];
  const float* classification = (const float*)d_in[2];
  const float* rotation       = (const float*)d_in[3];
  const float* tanch          = (const float*)d_in[4];
  const float* tdelta         = (const float*)d_in[5];
  float* out = (float*)d_out;

  char* ws = (char*)d_ws;
  size_t off = 0;
  auto alloc = [&](size_t bytes) -> void* {
    void* p = ws + off;
    off += (bytes + 255) & ~(size_t)255;
    return p;
  };
  float*    boxes  = (float*)alloc((size_t)NA * 4 * 4);
  float*    trn    = (float*)alloc((size_t)NA * 3 * 4);
  int*      counts = (int*)alloc(NC * CPAD * 4);
  u64*      cand   = (u64*)alloc((size_t)NC * CMAX * 8);
  u64*      topk   = (u64*)alloc((size_t)NC * PK * 8);
  unsigned* keep   = (unsigned*)alloc(NC * 32 * 4);

  hipMemsetAsync(counts, 0, NC * CPAD * 4, stream);

  k_decode<<<(NA + 255) / 256, 256, 0, stream>>>(
      (const float4*)anchors, (const float4*)regression, tanch, tdelta,
      (float4*)boxes, trn);
  k_collect<<<2048, 256, 0, stream>>>((const float4*)classification, counts, cand);

  hipFuncSetAttribute(reinterpret_cast<const void*>(k_sortnms),
                      hipFuncAttributeMaxDynamicSharedMemorySize, 131072);
  k_sortnms<<<NC, 1024, 131072, stream>>>(counts, cand, (const float4*)boxes, topk, keep);

  hipFuncSetAttribute(reinterpret_cast<const void*>(k_final),
                      hipFuncAttributeMaxDynamicSharedMemorySize, 131072);
  k_final<<<1, 1024, 131072, stream>>>(topk, keep, (const float4*)boxes, rotation, trn, out);
}

// Round 6
// 143.859 us; speedup vs baseline: 5.4732x; 1.1220x over previous
//
#include <hip/hip_runtime.h>

#define NA 150381
#define NC 90
#define PK 1024
#define CMAX 4096
#define MDET 100
#define STHR 0.996f
#define NTHR 0.5f
#define IMGF 896.0f
#define CPAD 32   // counts padded: one 128B cacheline per class
#define BCH 128   // sup-matrix build chunk (rows)

typedef unsigned long long u64;

// ---------------- decode boxes + translation ----------------
__global__ void k_decode(const float4* __restrict__ anc, const float4* __restrict__ reg,
                         const float* __restrict__ ta, const float* __restrict__ td,
                         float4* __restrict__ boxes, float* __restrict__ trn) {
  int i = blockIdx.x * blockDim.x + threadIdx.x;
  if (i >= NA) return;
  float4 a = anc[i];
  float4 r = reg[i];
  float cxa = (a.x + a.z) * 0.5f, cya = (a.y + a.w) * 0.5f;
  float wa = a.z - a.x, ha = a.w - a.y;
  float w = expf(r.w) * wa, h = expf(r.z) * ha;
  float cy = r.x * ha + cya, cx = r.y * wa + cxa;
  float4 b;
  b.x = fminf(fmaxf(cx - w * 0.5f, 0.f), IMGF);
  b.y = fminf(fmaxf(cy - h * 0.5f, 0.f), IMGF);
  b.z = fminf(fmaxf(cx + w * 0.5f, 0.f), IMGF);
  b.w = fminf(fmaxf(cy + h * 0.5f, 0.f), IMGF);
  boxes[i] = b;
  float st = ta[i*3+2];
  trn[i*3+0] = ta[i*3+0] + td[i*3+0] * st;
  trn[i*3+1] = ta[i*3+1] + td[i*3+1] * st;
  trn[i*3+2] = td[i*3+2];
}

// ---------------- threshold filter into per-class candidate lists ----------------
__global__ void k_collect(const float4* __restrict__ cls4, int* __restrict__ counts,
                          u64* __restrict__ cand) {
  const int total = NA * NC;
  const int nv4 = total >> 2;
  const int stride = gridDim.x * blockDim.x;
  for (int q = blockIdx.x * blockDim.x + threadIdx.x; q < nv4; q += stride) {
    float4 v4 = cls4[q];
    float vv[4] = {v4.x, v4.y, v4.z, v4.w};
    #pragma unroll
    for (int e = 0; e < 4; ++e) {
      float v = vv[e];
      if (v > STHR) {
        int f = q * 4 + e;
        int c = f % NC;
        int i = f / NC;
        int pos = atomicAdd(&counts[c * CPAD], 1);
        if (pos < CMAX)
          cand[(size_t)c * CMAX + pos] =
              ((u64)__float_as_uint(v) << 32) | (u64)(0xFFFFFFFFu - (unsigned)i);
      }
    }
  }
  int g = blockIdx.x * blockDim.x + threadIdx.x;
  if (g < total - nv4 * 4) {
    int f = nv4 * 4 + g;
    float v = ((const float*)cls4)[f];
    if (v > STHR) {
      int c = f % NC;
      int i = f / NC;
      int pos = atomicAdd(&counts[c * CPAD], 1);
      if (pos < CMAX)
        cand[(size_t)c * CMAX + pos] =
            ((u64)__float_as_uint(v) << 32) | (u64)(0xFFFFFFFFu - (unsigned)i);
    }
  }
}

__device__ __forceinline__ void bitonic_desc(u64* a, int n, int tid, int nth) {
  for (int k = 2; k <= n; k <<= 1) {
    for (int j = k >> 1; j > 0; j >>= 1) {
      __syncthreads();
      for (int i = tid; i < n; i += nth) {
        int ixj = i ^ j;
        if (ixj > i) {
          u64 x = a[i], y = a[ixj];
          if (((i & k) == 0) ? (x < y) : (x > y)) { a[i] = y; a[ixj] = x; }
        }
      }
    }
  }
  __syncthreads();
}

// ---------------- per-class sort -> topk (register bitonic, LDS for far passes) ----
__global__ __launch_bounds__(1024) void k_sort(const int* __restrict__ counts,
                                               const u64* __restrict__ cand,
                                               u64* __restrict__ topk,
                                               int* __restrict__ mcount) {
  extern __shared__ u64 sbuf[];   // 32 KB (CMAX u64 for fallback; 8KB used normally)
  const int c = blockIdx.x, tid = threadIdx.x;
  const int M = min(counts[c * CPAD], CMAX);
  u64 v;
  if (M <= PK) {
    v = (tid < M) ? cand[(size_t)c * CMAX + tid] : 0ULL;
    for (int k = 2; k <= PK; k <<= 1) {
      for (int j = k >> 1; j > 0; j >>= 1) {
        u64 p;
        if (j >= 64) {
          __syncthreads();
          sbuf[tid] = v;
          __syncthreads();
          p = sbuf[tid ^ j];
        } else {
          p = __shfl_xor(v, j, 64);
        }
        u64 mx = (v >= p) ? v : p, mn = (v >= p) ? p : v;
        bool takeMax = (((tid & k) == 0) != ((tid & j) != 0));
        v = takeMax ? mx : mn;
      }
    }
  } else {
    int NS = PK;
    while (NS < M) NS <<= 1;
    for (int k = tid; k < NS; k += 1024)
      sbuf[k] = (k < M) ? cand[(size_t)c * CMAX + k] : 0ULL;
    bitonic_desc(sbuf, NS, tid, 1024);
    v = sbuf[tid];
  }
  const int Mk = min(M, PK);
  if (tid < Mk) topk[(size_t)c * PK + tid] = v;
  if (tid == 0) mcount[c] = Mk;
}

// ---------------- per-class NMS: lazy chunked sup build + word-batched scan ----
// sup row layout swizzled: word w of row i at column (w+i)&31 (conflict-free).
// rowsup bit r = "row r suppresses someone" -> scan skips LDS reads for clean
// words entirely (whole 32-rank word kept in one step when no flagged row).
__global__ __launch_bounds__(1024) void k_nms(const int* __restrict__ mcount,
                                              const u64* __restrict__ topk,
                                              const float4* __restrict__ boxes,
                                              unsigned* __restrict__ keep_out) {
  extern __shared__ unsigned sup[];            // [PK][32] swizzled = 128 KB
  __shared__ float bx1[PK], by1[PK], bx2[PK], by2[PK], ar[PK];
  __shared__ unsigned rowsup[32];
  __shared__ int s_done;
  const int c = blockIdx.x, tid = threadIdx.x;
  const int Mk = mcount[c];

  if (tid < 32) rowsup[tid] = 0u;
  if (tid == 0) s_done = 0;
  if (tid < Mk) {
    u64 key = topk[(size_t)c * PK + tid];
    unsigned aidx = 0xFFFFFFFFu - (unsigned)(key & 0xFFFFFFFFull);
    float4 b = boxes[aidx];
    bx1[tid] = b.x; by1[tid] = b.y; bx2[tid] = b.z; by2[tid] = b.w;
    ar[tid] = (b.z - b.x) * (b.w - b.y);
  }
  __syncthreads();

  // scan state (persistent across chunks, wave 0)
  unsigned todo = 0, keep_acc = 0;
  if (tid < 32) {
    int lo = tid << 5;
    todo = (Mk <= lo) ? 0u : ((Mk - lo >= 32) ? 0xFFFFFFFFu : ((1u << (Mk - lo)) - 1u));
  }
  int kept_total = 0;

  const int NCH = (Mk + BCH - 1) / BCH;
  for (int ch = 0; ch < NCH; ++ch) {
    // ---- build chunk rows: 8 threads per row, full upper-triangle row ----
    {
      int r = ch * BCH + (tid >> 3);
      if (r < Mk) {
        const int s = tid & 7;
        const float x1 = bx1[r], y1 = by1[r], x2 = bx2[r], y2 = by2[r], ai = ar[r];
        const int nw = (Mk + 31) >> 5;
        const int w0 = r >> 5;
        unsigned any = 0;
        for (int w = s; w < nw; w += 8) {
          if (w < w0) continue;            // lower-triangle: never consulted
          unsigned word = 0;
          const int jb = w << 5;
          const int rot = s << 2;          // bank-rotated column order
          #pragma unroll 4
          for (int bb = 0; bb < 32; ++bb) {
            int b = (bb + rot) & 31;
            int j = jb + b;
            if (j > r && j < Mk) {
              float ix1 = fmaxf(x1, bx1[j]), iy1 = fmaxf(y1, by1[j]);
              float ix2 = fminf(x2, bx2[j]), iy2 = fminf(y2, by2[j]);
              float iw = fmaxf(ix2 - ix1, 0.f), ih = fmaxf(iy2 - iy1, 0.f);
              float inter = iw * ih;
              float uni = ai + ar[j] - inter;
              if (inter / fmaxf(uni, 1e-9f) > NTHR) word |= 1u << b;
            }
          }
          sup[(r << 5) + ((w + r) & 31)] = word;
          any |= word;
        }
        if (any) atomicOr(&rowsup[r >> 5], 1u << (r & 31));
      }
    }
    __syncthreads();

    // ---- word-batched kept-only scan over built region ----
    if (tid < 64) {
      unsigned rs = (tid < 32) ? rowsup[tid] : 0u;
      const int hi = min((ch + 1) * BCH, Mk);
      while (kept_total < MDET) {
        u64 bal = __ballot(todo != 0u);
        if (bal == 0ull) { if (tid == 0) s_done = 1; break; }
        int L = __ffsll(bal) - 1;
        if ((L << 5) >= hi) break;         // word not built yet
        unsigned ow = (unsigned)__builtin_amdgcn_readlane((int)todo, L);
        unsigned rsw = (unsigned)__builtin_amdgcn_readlane((int)rs, L) & ow;
        if (rsw == 0u) {
          // no row in this word suppresses anyone: keep the whole word
          int take = __popc(ow);
          int rem = MDET - kept_total;
          if (take <= rem) {
            if (tid == L) { keep_acc |= ow; todo = 0u; }
            kept_total += take;
          } else {
            unsigned sel = 0, tmp = ow;
            for (int q = 0; q < rem; ++q) { sel |= tmp & (0u - tmp); tmp &= tmp - 1u; }
            if (tid == L) { keep_acc |= sel; todo &= ~sel; }
            kept_total = MDET;
          }
          if (kept_total >= MDET && tid == 0) s_done = 1;
          continue;
        }
        // word contains suppressing rows: bit-serial, read only flagged rows
        while (ow != 0u && kept_total < MDET) {
          int b = __ffs(ow) - 1;
          int i = (L << 5) + b;
          unsigned bit = 1u << b;
          if (tid == L) { keep_acc |= bit; todo &= ~bit; }
          ow &= ~bit;
          kept_total++;
          if (rsw & bit) {
            unsigned srow = sup[(i << 5) + ((tid + i) & 31)];
            todo &= ~srow;
            unsigned sL = (unsigned)__builtin_amdgcn_readlane((int)srow, L);
            ow &= ~sL;
          }
        }
        if (kept_total >= MDET && tid == 0) s_done = 1;
      }
    }
    __syncthreads();
    if (s_done) break;
  }

  if (tid < 32) keep_out[(c << 5) + tid] = keep_acc;
}

// ---------------- global top-100 via radix-select + small sort + gather ----------------
__global__ __launch_bounds__(1024) void k_final(const u64* __restrict__ topk,
                                                const unsigned* __restrict__ keep,
                                                const float4* __restrict__ boxes,
                                                const float* __restrict__ rot,
                                                const float* __restrict__ trn,
                                                float* __restrict__ out) {
  extern __shared__ u64 buf[];                       // 16384 u64 = 131072 B
  u64* cand = buf;                                   // slots [0, 9000)
  unsigned* hist = (unsigned*)(buf + 9216);          // 8448 u32 bins
  u64* sbuf = (u64*)((char*)buf + 9216*8 + 8448*4);  // 1024 u64
  __shared__ unsigned kp[NC * 32];                   // keep words staged in LDS
  __shared__ unsigned short pw[NC * 32];             // per-word exclusive kept-prefix
  __shared__ unsigned wsum[16], wsuf[16];
  __shared__ int s_B, s_gc, s_gcnt;

  const int tid = threadIdx.x;
  const int wave = tid >> 6;
  const int lane = tid & 63;
  const unsigned SB = __float_as_uint(STHR);
  const int NB = (int)((0x3F800000u - SB) >> 3) + 1;  // ~8390 bins

  for (int t = tid; t < NC * MDET; t += 1024) cand[t] = 0ULL;
  for (int t = tid; t < NB; t += 1024) hist[t] = 0u;
  for (int t = tid; t < NC * 32; t += 1024) kp[t] = keep[t];
  if (tid == 0) s_gcnt = 0;
  __syncthreads();

  // per-class word-prefix popcounts (wave per class, shfl scan, no global loads)
  for (int c = wave; c < NC; c += 16) {
    if (lane < 32) {
      unsigned w = kp[c * 32 + lane];
      int pc = __popc(w);
      int scan = pc;
      for (int d = 1; d < 32; d <<= 1) {
        int v = __shfl_up(scan, d);
        if (lane >= d) scan += v;
      }
      pw[c * 32 + lane] = (unsigned short)(scan - pc);  // exclusive prefix
    }
  }
  __syncthreads();

  // parallel expansion: every kept (class, rank) computes its slot independently
  for (int t = tid; t < NC * PK; t += 1024) {
    int c = t >> 10, r = t & (PK - 1);
    unsigned w = kp[c * 32 + (r >> 5)];
    if ((w >> (r & 31)) & 1u) {
      int slot = (int)pw[c * 32 + (r >> 5)] + __popc(w & ((1u << (r & 31)) - 1u));
      if (slot < MDET) {
        u64 tkey = topk[(size_t)c * PK + r];
        unsigned flat = (unsigned)(c * PK + r);
        cand[c * MDET + slot] =
            (tkey & 0xFFFFFFFF00000000ull) | (u64)(0xFFFFFFFFu - flat);
      }
    }
  }
  __syncthreads();

  // histogram scores into bins
  for (int t = tid; t < NC * MDET; t += 1024) {
    u64 k = cand[t];
    if (k) atomicAdd(&hist[(int)(((unsigned)(k >> 32) - SB) >> 3)], 1u);
  }
  __syncthreads();

  // hierarchical suffix scan: chunk sums -> intra-wave shfl suffix -> 16-wave combine
  const int CH = (NB + 1023) >> 10;
  int clo = tid * CH, chi = min(clo + CH, NB);
  unsigned s = 0;
  for (int bb = clo; bb < chi; ++bb) s += hist[bb];
  unsigned ss = s;
  for (int d = 1; d < 64; d <<= 1) {
    unsigned v = __shfl_down(ss, d);
    if (lane + d < 64) ss += v;
  }
  if (lane == 0) wsum[wave] = ss;
  __syncthreads();
  if (tid < 16) {
    unsigned t = wsum[tid];
    for (int d = 1; d < 16; d <<= 1) {
      unsigned v = __shfl_down(t, d);
      if (tid + d < 16) t += v;
    }
    wsuf[tid] = t;
  }
  __syncthreads();
  unsigned suff = ss + ((wave < 15) ? wsuf[wave + 1] : 0u);
  unsigned suffn = suff - s;
  if (tid == 0 && wsuf[0] < MDET) { s_B = 0; s_gc = (int)wsuf[0]; }
  if (suff >= MDET && suffn < MDET) {
    unsigned after = suffn;
    int Bf = clo;
    for (int bb = chi - 1; bb >= clo; --bb) {
      after += hist[bb];
      if (after >= MDET) { Bf = bb; break; }
    }
    s_B = Bf; s_gc = (int)after;
  }
  __syncthreads();
  const int B = s_B, gc = s_gc;

  u64* sel;
  if (gc <= 1024) {
    int NSf = 128;
    while (NSf < gc) NSf <<= 1;
    for (int t = tid; t < NSf; t += 1024) sbuf[t] = 0ULL;
    __syncthreads();
    for (int t = tid; t < NC * MDET; t += 1024) {
      u64 k = cand[t];
      if (k && (int)(((unsigned)(k >> 32) - SB) >> 3) >= B)
        sbuf[atomicAdd(&s_gcnt, 1)] = k;
    }
    __syncthreads();
    bitonic_desc(sbuf, NSf, tid, 1024);
    sel = sbuf;
  } else {
    for (int t = tid; t < 16384; t += 1024)
      if (t >= NC * MDET) buf[t] = 0ULL;
    __syncthreads();
    bitonic_desc(buf, 16384, tid, 1024);
    sel = buf;
  }

  // gather top-100 outputs
  if (tid < MDET) {
    u64 key = sel[tid];
    bool ok = (key != 0ULL);
    float b0 = -1.f, b1 = -1.f, b2 = -1.f, b3 = -1.f;
    float r0 = -1.f, r1 = -1.f, r2 = -1.f;
    float t0 = -1.f, t1 = -1.f, t2 = -1.f;
    float sc = -1.f, lab = -1.f;
    if (ok) {
      float score = __uint_as_float((unsigned)(key >> 32));
      unsigned flat = 0xFFFFFFFFu - (unsigned)(key & 0xFFFFFFFFull);
      int c = flat >> 10, pos = flat & 1023;
      u64 tkey = topk[(size_t)c * PK + pos];
      unsigned aidx = 0xFFFFFFFFu - (unsigned)(tkey & 0xFFFFFFFFull);
      float4 bb = boxes[aidx];
      b0 = bb.x; b1 = bb.y; b2 = bb.z; b3 = bb.w;
      sc = score; lab = (float)c;
      r0 = rot[aidx*3+0]; r1 = rot[aidx*3+1]; r2 = rot[aidx*3+2];
      t0 = trn[aidx*3+0]; t1 = trn[aidx*3+1]; t2 = trn[aidx*3+2];
    }
    out[tid*4+0] = b0; out[tid*4+1] = b1; out[tid*4+2] = b2; out[tid*4+3] = b3;
    out[400 + tid] = sc;
    out[500 + tid] = lab;
    out[600 + tid*3+0] = r0; out[600 + tid*3+1] = r1; out[600 + tid*3+2] = r2;
    out[900 + tid*3+0] = t0; out[900 + tid*3+1] = t1; out[900 + tid*3+2] = t2;
  }
}

extern "C" void kernel_launch(void* const* d_in, const int* in_sizes, int n_in,
                              void* d_out, int out_size, void* d_ws, size_t ws_size,
                              hipStream_t stream) {
  const float* anchors        = (const float*)d_in[0];
  const float* regression     = (const float*)d_in[1];
  const float* classification = (const float*)d_in[2];
  const float* rotation       = (const float*)d_in[3];
  const float* tanch          = (const float*)d_in[4];
  const float* tdelta         = (const float*)d_in[5];
  float* out = (float*)d_out;

  char* ws = (char*)d_ws;
  size_t off = 0;
  auto alloc = [&](size_t bytes) -> void* {
    void* p = ws + off;
    off += (bytes + 255) & ~(size_t)255;
    return p;
  };
  float*    boxes  = (float*)alloc((size_t)NA * 4 * 4);
  float*    trn    = (float*)alloc((size_t)NA * 3 * 4);
  int*      counts = (int*)alloc(NC * CPAD * 4);
  int*      mcount = (int*)alloc(NC * 4);
  u64*      cand   = (u64*)alloc((size_t)NC * CMAX * 8);
  u64*      topk   = (u64*)alloc((size_t)NC * PK * 8);
  unsigned* keep   = (unsigned*)alloc(NC * 32 * 4);

  hipMemsetAsync(counts, 0, NC * CPAD * 4, stream);

  k_decode<<<(NA + 255) / 256, 256, 0, stream>>>(
      (const float4*)anchors, (const float4*)regression, tanch, tdelta,
      (float4*)boxes, trn);
  k_collect<<<2048, 256, 0, stream>>>((const float4*)classification, counts, cand);

  hipFuncSetAttribute(reinterpret_cast<const void*>(k_sort),
                      hipFuncAttributeMaxDynamicSharedMemorySize, CMAX * 8);
  k_sort<<<NC, 1024, CMAX * 8, stream>>>(counts, cand, topk, mcount);

  hipFuncSetAttribute(reinterpret_cast<const void*>(k_nms),
                      hipFuncAttributeMaxDynamicSharedMemorySize, 131072);
  k_nms<<<NC, 1024, 131072, stream>>>(mcount, topk, (const float4*)boxes, keep);

  hipFuncSetAttribute(reinterpret_cast<const void*>(k_final),
                      hipFuncAttributeMaxDynamicSharedMemorySize, 131072);
  k_final<<<1, 1024, 131072, stream>>>(topk, keep, (const float4*)boxes, rotation, trn, out);
}

// Round 7
// 118.732 us; speedup vs baseline: 6.6315x; 1.2116x over previous
//
#include <hip/hip_runtime.h>

#define NA 150381
#define NC 90
#define PK 1024
#define CMAX 4096
#define MDET 100
#define STHR 0.996f
#define NTHR 0.5f
#define IMGF 896.0f
#define CPAD 32   // counts padded: one 128B cacheline per class

typedef unsigned long long u64;

// ---------------- decode boxes + translation ----------------
__global__ void k_decode(const float4* __restrict__ anc, const float4* __restrict__ reg,
                         const float* __restrict__ ta, const float* __restrict__ td,
                         float4* __restrict__ boxes, float* __restrict__ trn) {
  int i = blockIdx.x * blockDim.x + threadIdx.x;
  if (i >= NA) return;
  float4 a = anc[i];
  float4 r = reg[i];
  float cxa = (a.x + a.z) * 0.5f, cya = (a.y + a.w) * 0.5f;
  float wa = a.z - a.x, ha = a.w - a.y;
  float w = expf(r.w) * wa, h = expf(r.z) * ha;
  float cy = r.x * ha + cya, cx = r.y * wa + cxa;
  float4 b;
  b.x = fminf(fmaxf(cx - w * 0.5f, 0.f), IMGF);
  b.y = fminf(fmaxf(cy - h * 0.5f, 0.f), IMGF);
  b.z = fminf(fmaxf(cx + w * 0.5f, 0.f), IMGF);
  b.w = fminf(fmaxf(cy + h * 0.5f, 0.f), IMGF);
  boxes[i] = b;
  float st = ta[i*3+2];
  trn[i*3+0] = ta[i*3+0] + td[i*3+0] * st;
  trn[i*3+1] = ta[i*3+1] + td[i*3+1] * st;
  trn[i*3+2] = td[i*3+2];
}

// ---------------- threshold filter into per-class candidate lists ----------------
__global__ void k_collect(const float4* __restrict__ cls4, int* __restrict__ counts,
                          u64* __restrict__ cand) {
  const int total = NA * NC;
  const int nv4 = total >> 2;
  const int stride = gridDim.x * blockDim.x;
  for (int q = blockIdx.x * blockDim.x + threadIdx.x; q < nv4; q += stride) {
    float4 v4 = cls4[q];
    float vv[4] = {v4.x, v4.y, v4.z, v4.w};
    #pragma unroll
    for (int e = 0; e < 4; ++e) {
      float v = vv[e];
      if (v > STHR) {
        int f = q * 4 + e;
        int c = f % NC;
        int i = f / NC;
        int pos = atomicAdd(&counts[c * CPAD], 1);
        if (pos < CMAX)
          cand[(size_t)c * CMAX + pos] =
              ((u64)__float_as_uint(v) << 32) | (u64)(0xFFFFFFFFu - (unsigned)i);
      }
    }
  }
  int g = blockIdx.x * blockDim.x + threadIdx.x;
  if (g < total - nv4 * 4) {
    int f = nv4 * 4 + g;
    float v = ((const float*)cls4)[f];
    if (v > STHR) {
      int c = f % NC;
      int i = f / NC;
      int pos = atomicAdd(&counts[c * CPAD], 1);
      if (pos < CMAX)
        cand[(size_t)c * CMAX + pos] =
            ((u64)__float_as_uint(v) << 32) | (u64)(0xFFFFFFFFu - (unsigned)i);
    }
  }
}

__device__ __forceinline__ void bitonic_desc(u64* a, int n, int tid, int nth) {
  for (int k = 2; k <= n; k <<= 1) {
    for (int j = k >> 1; j > 0; j >>= 1) {
      __syncthreads();
      for (int i = tid; i < n; i += nth) {
        int ixj = i ^ j;
        if (ixj > i) {
          u64 x = a[i], y = a[ixj];
          if (((i & k) == 0) ? (x < y) : (x > y)) { a[i] = y; a[ixj] = x; }
        }
      }
    }
  }
  __syncthreads();
}

// ---------------- fused per-class sort + window-greedy NMS (no sup matrix) ----
// Thread t owns rank t after the register bitonic sort. Greedy NMS done as:
//   Phase A (parallel): per-lane 64-bit intra-window suppression rowmask.
//   Phase B (serial over 64-rank windows, early-capped at MDET kept):
//     wave ww resolves its window in registers (ffs + shfl chain, no LDS),
//     then all later-window lanes cross-suppress vs the <=64 kept boxes
//     (broadcast LDS reads). One barrier per resolved window.
__global__ __launch_bounds__(1024) void k_classnms(const int* __restrict__ counts,
                                                   const u64* __restrict__ cand,
                                                   const float4* __restrict__ boxes,
                                                   u64* __restrict__ topk,
                                                   unsigned* __restrict__ keep_out) {
  __shared__ u64 sbuf[CMAX];                     // 32 KB sort scratch
  __shared__ float bx1[PK], by1[PK], bx2[PK], by2[PK], ar[PK];  // 20 KB
  __shared__ u64 s_kept[16];
  __shared__ int s_totw[16];
  const int c = blockIdx.x, tid = threadIdx.x;
  const int w = tid >> 6, l = tid & 63;

  const int M = min(counts[c * CPAD], CMAX);

  // ---- sort: element-per-thread bitonic; shfl for j<64, LDS for j>=64 ----
  u64 v;
  if (M <= PK) {
    v = (tid < M) ? cand[(size_t)c * CMAX + tid] : 0ULL;
    for (int k = 2; k <= PK; k <<= 1) {
      for (int j = k >> 1; j > 0; j >>= 1) {
        u64 p;
        if (j >= 64) {
          __syncthreads();
          sbuf[tid] = v;
          __syncthreads();
          p = sbuf[tid ^ j];
        } else {
          p = __shfl_xor(v, j, 64);
        }
        u64 mx = (v >= p) ? v : p, mn = (v >= p) ? p : v;
        bool takeMax = (((tid & k) == 0) != ((tid & j) != 0));
        v = takeMax ? mx : mn;
      }
    }
  } else {
    int NS = PK;
    while (NS < M) NS <<= 1;
    for (int k = tid; k < NS; k += 1024)
      sbuf[k] = (k < M) ? cand[(size_t)c * CMAX + k] : 0ULL;
    bitonic_desc(sbuf, NS, tid, 1024);
    v = sbuf[tid];
  }

  const int Mk = min(M, PK);
  bool alive = (tid < Mk);
  float mx1 = 0.f, my1 = 0.f, mx2 = 0.f, my2 = 0.f, mar = 0.f;
  if (tid < Mk) {
    topk[(size_t)c * PK + tid] = v;
    unsigned aidx = 0xFFFFFFFFu - (unsigned)(v & 0xFFFFFFFFull);
    float4 b = boxes[aidx];
    mx1 = b.x; my1 = b.y; mx2 = b.z; my2 = b.w;
    mar = (b.z - b.x) * (b.w - b.y);
    bx1[tid] = b.x; by1[tid] = b.y; bx2[tid] = b.z; by2[tid] = b.w; ar[tid] = mar;
  }
  if (tid < 16) { s_kept[tid] = 0ULL; s_totw[tid] = 0; }
  __syncthreads();

  // ---- Phase A: intra-window suppression rowmask (bits m > l only) ----
  u64 rowmask = 0;
  if (tid < Mk) {
    const int base = w << 6;
    const int jend = min(Mk - base, 64);
    for (int m = l + 1; m < jend; ++m) {
      int j = base + m;
      float ix1 = fmaxf(mx1, bx1[j]), iy1 = fmaxf(my1, by1[j]);
      float ix2 = fminf(mx2, bx2[j]), iy2 = fminf(my2, by2[j]);
      float iw = fmaxf(ix2 - ix1, 0.f), ih = fmaxf(iy2 - iy1, 0.f);
      float inter = iw * ih;
      float uni = mar + ar[j] - inter;
      if (inter / fmaxf(uni, 1e-9f) > NTHR) rowmask |= 1ULL << m;
    }
  }

  // ---- Phase B: serial window resolution, capped at MDET kept ----
  const int nwin = (Mk + 63) >> 6;
  for (int ww = 0; ww < nwin; ++ww) {
    if (w == ww) {
      int total = (ww == 0) ? 0 : s_totw[ww - 1];
      u64 cur = __ballot(alive);
      u64 kept64 = 0;
      while (cur != 0ULL && total < MDET) {
        int b = __ffsll((unsigned long long)cur) - 1;
        kept64 |= 1ULL << b;
        ++total;
        u64 rm = __shfl(rowmask, b, 64);     // broadcast row b's mask
        cur &= ~rm;
        cur &= ~(1ULL << b);
      }
      alive = ((kept64 >> l) & 1ULL) != 0ULL;
      if (l == 0) { s_kept[ww] = kept64; s_totw[ww] = total; }
    }
    __syncthreads();
    const u64 kk = s_kept[ww];
    if (alive && w > ww && kk != 0ULL) {
      u64 t64 = kk;
      const int base = ww << 6;
      while (t64) {
        int b = __ffsll((unsigned long long)t64) - 1;
        t64 &= t64 - 1ULL;
        int i = base + b;
        float ix1 = fmaxf(bx1[i], mx1), iy1 = fmaxf(by1[i], my1);
        float ix2 = fminf(bx2[i], mx2), iy2 = fminf(by2[i], my2);
        float iw = fmaxf(ix2 - ix1, 0.f), ih = fmaxf(iy2 - iy1, 0.f);
        float inter = iw * ih;
        float uni = ar[i] + mar - inter;
        if (inter / fmaxf(uni, 1e-9f) > NTHR) { alive = false; break; }
      }
    }
    if (s_totw[ww] >= MDET) break;
  }

  if (tid < 16) {
    u64 kk = s_kept[tid];
    keep_out[(c << 5) + 2 * tid]     = (unsigned)(kk & 0xFFFFFFFFULL);
    keep_out[(c << 5) + 2 * tid + 1] = (unsigned)(kk >> 32);
  }
}

// ---------------- global top-100 via radix-select + small sort + gather ----------------
__global__ __launch_bounds__(1024) void k_final(const u64* __restrict__ topk,
                                                const unsigned* __restrict__ keep,
                                                const float4* __restrict__ boxes,
                                                const float* __restrict__ rot,
                                                const float* __restrict__ trn,
                                                float* __restrict__ out) {
  extern __shared__ u64 buf[];                       // 16384 u64 = 131072 B
  u64* cand = buf;                                   // slots [0, 9000)
  unsigned* hist = (unsigned*)(buf + 9216);          // 8448 u32 bins
  u64* sbuf = (u64*)((char*)buf + 9216*8 + 8448*4);  // 1024 u64
  __shared__ unsigned kp[NC * 32];                   // keep words staged in LDS
  __shared__ unsigned short pw[NC * 32];             // per-word exclusive kept-prefix
  __shared__ unsigned wsum[16], wsuf[16];
  __shared__ int s_B, s_gc, s_gcnt;

  const int tid = threadIdx.x;
  const int wave = tid >> 6;
  const int lane = tid & 63;
  const unsigned SB = __float_as_uint(STHR);
  const int NB = (int)((0x3F800000u - SB) >> 3) + 1;  // ~8390 bins

  for (int t = tid; t < NC * MDET; t += 1024) cand[t] = 0ULL;
  for (int t = tid; t < NB; t += 1024) hist[t] = 0u;
  for (int t = tid; t < NC * 32; t += 1024) kp[t] = keep[t];
  if (tid == 0) s_gcnt = 0;
  __syncthreads();

  // per-class word-prefix popcounts (wave per class, shfl scan)
  for (int c = wave; c < NC; c += 16) {
    if (lane < 32) {
      unsigned w = kp[c * 32 + lane];
      int pc = __popc(w);
      int scan = pc;
      for (int d = 1; d < 32; d <<= 1) {
        int v = __shfl_up(scan, d);
        if (lane >= d) scan += v;
      }
      pw[c * 32 + lane] = (unsigned short)(scan - pc);  // exclusive prefix
    }
  }
  __syncthreads();

  // parallel expansion: every kept (class, rank) computes its slot independently
  for (int t = tid; t < NC * PK; t += 1024) {
    int c = t >> 10, r = t & (PK - 1);
    unsigned w = kp[c * 32 + (r >> 5)];
    if ((w >> (r & 31)) & 1u) {
      int slot = (int)pw[c * 32 + (r >> 5)] + __popc(w & ((1u << (r & 31)) - 1u));
      if (slot < MDET) {
        u64 tkey = topk[(size_t)c * PK + r];
        unsigned flat = (unsigned)(c * PK + r);
        cand[c * MDET + slot] =
            (tkey & 0xFFFFFFFF00000000ull) | (u64)(0xFFFFFFFFu - flat);
      }
    }
  }
  __syncthreads();

  // histogram scores into bins
  for (int t = tid; t < NC * MDET; t += 1024) {
    u64 k = cand[t];
    if (k) atomicAdd(&hist[(int)(((unsigned)(k >> 32) - SB) >> 3)], 1u);
  }
  __syncthreads();

  // hierarchical suffix scan
  const int CH = (NB + 1023) >> 10;
  int clo = tid * CH, chi = min(clo + CH, NB);
  unsigned s = 0;
  for (int bb = clo; bb < chi; ++bb) s += hist[bb];
  unsigned ss = s;
  for (int d = 1; d < 64; d <<= 1) {
    unsigned v = __shfl_down(ss, d);
    if (lane + d < 64) ss += v;
  }
  if (lane == 0) wsum[wave] = ss;
  __syncthreads();
  if (tid < 16) {
    unsigned t = wsum[tid];
    for (int d = 1; d < 16; d <<= 1) {
      unsigned v = __shfl_down(t, d);
      if (tid + d < 16) t += v;
    }
    wsuf[tid] = t;
  }
  __syncthreads();
  unsigned suff = ss + ((wave < 15) ? wsuf[wave + 1] : 0u);
  unsigned suffn = suff - s;
  if (tid == 0 && wsuf[0] < MDET) { s_B = 0; s_gc = (int)wsuf[0]; }
  if (suff >= MDET && suffn < MDET) {
    unsigned after = suffn;
    int Bf = clo;
    for (int bb = chi - 1; bb >= clo; --bb) {
      after += hist[bb];
      if (after >= MDET) { Bf = bb; break; }
    }
    s_B = Bf; s_gc = (int)after;
  }
  __syncthreads();
  const int B = s_B, gc = s_gc;

  u64* sel;
  if (gc <= 1024) {
    int NSf = 128;
    while (NSf < gc) NSf <<= 1;
    for (int t = tid; t < NSf; t += 1024) sbuf[t] = 0ULL;
    __syncthreads();
    for (int t = tid; t < NC * MDET; t += 1024) {
      u64 k = cand[t];
      if (k && (int)(((unsigned)(k >> 32) - SB) >> 3) >= B)
        sbuf[atomicAdd(&s_gcnt, 1)] = k;
    }
    __syncthreads();
    bitonic_desc(sbuf, NSf, tid, 1024);
    sel = sbuf;
  } else {
    for (int t = tid; t < 16384; t += 1024)
      if (t >= NC * MDET) buf[t] = 0ULL;
    __syncthreads();
    bitonic_desc(buf, 16384, tid, 1024);
    sel = buf;
  }

  // gather top-100 outputs
  if (tid < MDET) {
    u64 key = sel[tid];
    bool ok = (key != 0ULL);
    float b0 = -1.f, b1 = -1.f, b2 = -1.f, b3 = -1.f;
    float r0 = -1.f, r1 = -1.f, r2 = -1.f;
    float t0 = -1.f, t1 = -1.f, t2 = -1.f;
    float sc = -1.f, lab = -1.f;
    if (ok) {
      float score = __uint_as_float((unsigned)(key >> 32));
      unsigned flat = 0xFFFFFFFFu - (unsigned)(key & 0xFFFFFFFFull);
      int c = flat >> 10, pos = flat & 1023;
      u64 tkey = topk[(size_t)c * PK + pos];
      unsigned aidx = 0xFFFFFFFFu - (unsigned)(tkey & 0xFFFFFFFFull);
      float4 bb = boxes[aidx];
      b0 = bb.x; b1 = bb.y; b2 = bb.z; b3 = bb.w;
      sc = score; lab = (float)c;
      r0 = rot[aidx*3+0]; r1 = rot[aidx*3+1]; r2 = rot[aidx*3+2];
      t0 = trn[aidx*3+0]; t1 = trn[aidx*3+1]; t2 = trn[aidx*3+2];
    }
    out[tid*4+0] = b0; out[tid*4+1] = b1; out[tid*4+2] = b2; out[tid*4+3] = b3;
    out[400 + tid] = sc;
    out[500 + tid] = lab;
    out[600 + tid*3+0] = r0; out[600 + tid*3+1] = r1; out[600 + tid*3+2] = r2;
    out[900 + tid*3+0] = t0; out[900 + tid*3+1] = t1; out[900 + tid*3+2] = t2;
  }
}

extern "C" void kernel_launch(void* const* d_in, const int* in_sizes, int n_in,
                              void* d_out, int out_size, void* d_ws, size_t ws_size,
                              hipStream_t stream) {
  const float* anchors        = (const float*)d_in[0];
  const float* regression     = (const float*)d_in[1];
  const float* classification = (const float*)d_in[2];
  const float* rotation       = (const float*)d_in[3];
  const float* tanch          = (const float*)d_in[4];
  const float* tdelta         = (const float*)d_in[5];
  float* out = (float*)d_out;

  char* ws = (char*)d_ws;
  size_t off = 0;
  auto alloc = [&](size_t bytes) -> void* {
    void* p = ws + off;
    off += (bytes + 255) & ~(size_t)255;
    return p;
  };
  float*    boxes  = (float*)alloc((size_t)NA * 4 * 4);
  float*    trn    = (float*)alloc((size_t)NA * 3 * 4);
  int*      counts = (int*)alloc(NC * CPAD * 4);
  u64*      cand   = (u64*)alloc((size_t)NC * CMAX * 8);
  u64*      topk   = (u64*)alloc((size_t)NC * PK * 8);
  unsigned* keep   = (unsigned*)alloc(NC * 32 * 4);

  hipMemsetAsync(counts, 0, NC * CPAD * 4, stream);

  k_decode<<<(NA + 255) / 256, 256, 0, stream>>>(
      (const float4*)anchors, (const float4*)regression, tanch, tdelta,
      (float4*)boxes, trn);
  k_collect<<<2048, 256, 0, stream>>>((const float4*)classification, counts, cand);

  k_classnms<<<NC, 1024, 0, stream>>>(counts, cand, (const float4*)boxes, topk, keep);

  hipFuncSetAttribute(reinterpret_cast<const void*>(k_final),
                      hipFuncAttributeMaxDynamicSharedMemorySize, 131072);
  k_final<<<1, 1024, 131072, stream>>>(topk, keep, (const float4*)boxes, rotation, trn, out);
}

// Round 8
// 86.878 us; speedup vs baseline: 9.0629x; 1.3666x over previous
//
#include <hip/hip_runtime.h>

#define NA 150381
#define NC 90
#define PK 1024
#define CMAX 4096
#define MDET 100
#define STHR 0.996f
#define NTHR 0.5f
#define IMGF 896.0f
#define CPAD 32    // counts padded: one 128B cacheline per class
#define NBC 264    // per-class selection histogram bins (span>>8, padded)
#define NBF 1056   // final top-100 histogram bins (span>>6, padded)
#define SELT 192   // per-class selection target (>= MDET + suppression slack)

typedef unsigned long long u64;

__device__ __forceinline__ int binc(unsigned bits, unsigned SB) {
  int b = (int)((bits - SB) >> 8);
  return b < NBC - 1 ? b : NBC - 1;
}
__device__ __forceinline__ int binf(unsigned bits, unsigned SB) {
  int b = (int)((bits - SB) >> 6);
  return b < NBF - 1 ? b : NBF - 1;
}

// ---------------- decode boxes + translation; zero counts/histc ----------------
__global__ void k_decode(const float4* __restrict__ anc, const float4* __restrict__ reg,
                         const float* __restrict__ ta, const float* __restrict__ td,
                         float4* __restrict__ boxes, float* __restrict__ trn,
                         int* __restrict__ counts, int* __restrict__ histc) {
  int i = blockIdx.x * blockDim.x + threadIdx.x;
  // zeroing for the collect stage (this kernel precedes k_collect on the stream)
  if (i < NC * CPAD) counts[i] = 0;
  else if (i < NC * CPAD + NC * NBC) histc[i - NC * CPAD] = 0;
  if (i >= NA) return;
  float4 a = anc[i];
  float4 r = reg[i];
  float cxa = (a.x + a.z) * 0.5f, cya = (a.y + a.w) * 0.5f;
  float wa = a.z - a.x, ha = a.w - a.y;
  float w = expf(r.w) * wa, h = expf(r.z) * ha;
  float cy = r.x * ha + cya, cx = r.y * wa + cxa;
  float4 b;
  b.x = fminf(fmaxf(cx - w * 0.5f, 0.f), IMGF);
  b.y = fminf(fmaxf(cy - h * 0.5f, 0.f), IMGF);
  b.z = fminf(fmaxf(cx + w * 0.5f, 0.f), IMGF);
  b.w = fminf(fmaxf(cy + h * 0.5f, 0.f), IMGF);
  boxes[i] = b;
  float st = ta[i*3+2];
  trn[i*3+0] = ta[i*3+0] + td[i*3+0] * st;
  trn[i*3+1] = ta[i*3+1] + td[i*3+1] * st;
  trn[i*3+2] = td[i*3+2];
}

// ---------------- threshold filter into per-class lists + class histograms ------
__global__ void k_collect(const float4* __restrict__ cls4, int* __restrict__ counts,
                          u64* __restrict__ cand, int* __restrict__ histc) {
  const unsigned SB = __float_as_uint(STHR);
  const int total = NA * NC;
  const int nv4 = total >> 2;
  const int stride = gridDim.x * blockDim.x;
  for (int q = blockIdx.x * blockDim.x + threadIdx.x; q < nv4; q += stride) {
    float4 v4 = cls4[q];
    float vv[4] = {v4.x, v4.y, v4.z, v4.w};
    #pragma unroll
    for (int e = 0; e < 4; ++e) {
      float v = vv[e];
      if (v > STHR) {
        int f = q * 4 + e;
        int c = f % NC;
        int i = f / NC;
        unsigned bits = __float_as_uint(v);
        int pos = atomicAdd(&counts[c * CPAD], 1);
        if (pos < CMAX)
          cand[(size_t)c * CMAX + pos] =
              ((u64)bits << 32) | (u64)(0xFFFFFFFFu - (unsigned)i);
        atomicAdd(&histc[c * NBC + binc(bits, SB)], 1);
      }
    }
  }
  int g = blockIdx.x * blockDim.x + threadIdx.x;
  if (g < total - nv4 * 4) {
    int f = nv4 * 4 + g;
    float v = ((const float*)cls4)[f];
    if (v > STHR) {
      int c = f % NC;
      int i = f / NC;
      unsigned bits = __float_as_uint(v);
      int pos = atomicAdd(&counts[c * CPAD], 1);
      if (pos < CMAX)
        cand[(size_t)c * CMAX + pos] =
            ((u64)bits << 32) | (u64)(0xFFFFFFFFu - (unsigned)i);
      atomicAdd(&histc[c * NBC + binc(bits, SB)], 1);
    }
  }
}

__device__ __forceinline__ void bitonic_desc(u64* a, int n, int tid, int nth) {
  for (int k = 2; k <= n; k <<= 1) {
    for (int j = k >> 1; j > 0; j >>= 1) {
      __syncthreads();
      for (int i = tid; i < n; i += nth) {
        int ixj = i ^ j;
        if (ixj > i) {
          u64 x = a[i], y = a[ixj];
          if (((i & k) == 0) ? (x < y) : (x > y)) { a[i] = y; a[ixj] = x; }
        }
      }
    }
  }
  __syncthreads();
}

// ---------------- per-class: radix-select top~192 -> 1-wave sort -> window NMS ----
// Writes final per-class results directly: det[c*MDET+slot] (score | ~(c*MDET+slot))
// and aux[c*MDET+slot] = anchor index. Index field preserves reference tie order
// (slot<->pos monotone within class; class-major across classes).
__global__ __launch_bounds__(256) void k_classnms(const int* __restrict__ counts,
                                                  const u64* __restrict__ cand,
                                                  const int* __restrict__ histc,
                                                  const float4* __restrict__ boxes,
                                                  u64* __restrict__ det,
                                                  unsigned* __restrict__ aux,
                                                  int* __restrict__ flags) {
  __shared__ u64 sel[256];
  __shared__ float sx1[256], sy1[256], sx2[256], sy2[256], sar[256];
  __shared__ int s_B, s_gc, s_cnt;
  __shared__ u64 s_kept[4];
  __shared__ int s_totw[4];
  const int c = blockIdx.x, tid = threadIdx.x;
  const int w = tid >> 6, l = tid & 63;
  const unsigned SB = __float_as_uint(STHR);
  const int M = min(counts[c * CPAD], CMAX);

  if (tid < MDET) det[c * MDET + tid] = 0ULL;   // zero my det row (tail must be 0)
  if (tid < 4) { s_kept[tid] = 0ULL; s_totw[tid] = 0; }
  if (tid == 0) s_cnt = 0;
  sel[tid] = 0ULL;

  // ---- selection threshold from class histogram (wave 0, top-down chunk scan) ----
  if (tid < 64) {
    int R = 0, B = 0, gcv = 0;
    for (int q = (NBC - 1) >> 6; q >= 0; --q) {
      int b = (q << 6) + l;
      int h = (b < NBC) ? histc[c * NBC + b] : 0;
      int suf = h;
      for (int d = 1; d < 64; d <<= 1) {
        int v = __shfl_down(suf, d);
        if (l + d < 64) suf += v;
      }
      int ctot = __shfl(suf, 0);
      int sufn = suf - h;
      u64 hit = __ballot((suf + R >= SELT) && (sufn + R < SELT));
      if (hit != 0ULL) {
        int l0 = __ffsll(hit) - 1;
        B = (q << 6) + l0;
        gcv = __shfl(suf, l0) + R;
        break;
      }
      R += ctot;
      if (q == 0) { B = 0; gcv = R; }   // total < SELT: take all
    }
    if (l == 0) { s_B = B; s_gc = gcv; }
  }
  __syncthreads();
  const int B = s_B;
  if (s_gc > 256) {                      // tie pileup: exact fallback in k_final
    if (tid == 0) flags[c] = 1;
    return;
  }

  // ---- gather selected candidates (strictly separated by score bits from rest) ----
  for (int t = tid; t < M; t += 256) {
    u64 k = cand[(size_t)c * CMAX + t];
    if (binc((unsigned)(k >> 32), SB) >= B) {
      int p = atomicAdd(&s_cnt, 1);
      if (p < 256) sel[p] = k;
    }
  }
  __syncthreads();
  const int gc = min(s_cnt, 256);

  // ---- sort 256 slots in ONE wave: 4 regs/lane, shfl + local swaps, no barriers ----
  if (tid < 64 && gc > 0) {
    u64 ea = sel[l], eb = sel[64 + l], ec = sel[128 + l], ed = sel[192 + l];
    auto CSWL = [&](u64& lo, u64& hi, int ilow, int k) {
      bool tml = ((ilow & k) == 0);
      u64 mx = lo >= hi ? lo : hi, mn = lo >= hi ? hi : lo;
      lo = tml ? mx : mn; hi = tml ? mn : mx;
    };
    auto SH = [&](u64& x, int ibase, int j, int k) {
      u64 p = __shfl_xor(x, j, 64);
      bool tm = ((((ibase | l) & k) == 0) != ((l & j) != 0));
      u64 mx = x >= p ? x : p, mn = x >= p ? p : x;
      x = tm ? mx : mn;
    };
    for (int k = 2; k <= 256; k <<= 1) {
      for (int j = k >> 1; j > 0; j >>= 1) {
        if (j == 128)      { CSWL(ea, ec, l, k);       CSWL(eb, ed, 64 | l, k); }
        else if (j == 64)  { CSWL(ea, eb, l, k);       CSWL(ec, ed, 128 | l, k); }
        else { SH(ea, 0, j, k); SH(eb, 64, j, k); SH(ec, 128, j, k); SH(ed, 192, j, k); }
      }
    }
    sel[l] = ea; sel[64 + l] = eb; sel[128 + l] = ec; sel[192 + l] = ed;
  }
  __syncthreads();

  // ---- stage boxes for ranks [0, gc) ----
  const bool has = (tid < gc);
  u64 myk = 0; unsigned myaidx = 0;
  float mx1 = 0.f, my1 = 0.f, mx2 = 0.f, my2 = 0.f, mar = 0.f;
  if (has) {
    myk = sel[tid];
    myaidx = 0xFFFFFFFFu - (unsigned)(myk & 0xFFFFFFFFull);
    float4 b = boxes[myaidx];
    mx1 = b.x; my1 = b.y; mx2 = b.z; my2 = b.w;
    mar = (b.z - b.x) * (b.w - b.y);
    sx1[tid] = b.x; sy1[tid] = b.y; sx2[tid] = b.z; sy2[tid] = b.w; sar[tid] = mar;
  }
  __syncthreads();

  // ---- Phase A: intra-window suppression rowmask ----
  u64 rowmask = 0;
  if (has) {
    const int base = w << 6;
    const int jend = min(gc - base, 64);
    for (int m = l + 1; m < jend; ++m) {
      int j = base + m;
      float ix1 = fmaxf(mx1, sx1[j]), iy1 = fmaxf(my1, sy1[j]);
      float ix2 = fminf(mx2, sx2[j]), iy2 = fminf(my2, sy2[j]);
      float iw = fmaxf(ix2 - ix1, 0.f), ih = fmaxf(iy2 - iy1, 0.f);
      float inter = iw * ih;
      float uni = mar + sar[j] - inter;
      if (inter / fmaxf(uni, 1e-9f) > NTHR) rowmask |= 1ULL << m;
    }
  }

  // ---- Phase B: serial window resolution + direct det/aux writes ----
  bool alive = has;
  int finaltot = 0;
  bool capped = false;
  const int nwin = (gc + 63) >> 6;
  for (int ww = 0; ww < nwin; ++ww) {
    if (w == ww) {
      int tbase = (ww == 0) ? 0 : s_totw[ww - 1];
      int total = tbase;
      u64 cur = __ballot(alive);
      u64 kept64 = 0;
      while (cur != 0ULL && total < MDET) {
        int b = __ffsll(cur) - 1;
        kept64 |= 1ULL << b;
        ++total;
        u64 rm = __shfl(rowmask, b, 64);
        cur &= ~rm;
        cur &= ~(1ULL << b);
      }
      alive = ((kept64 >> l) & 1ULL) != 0ULL;
      if (alive) {
        int slot = tbase + __popcll(kept64 & ((1ULL << l) - 1ULL));
        if (slot < MDET) {
          int idx = c * MDET + slot;
          det[idx] = (myk & 0xFFFFFFFF00000000ull) | (u64)(0xFFFFFFFFu - (unsigned)idx);
          aux[idx] = myaidx;
        }
      }
      if (l == 0) { s_kept[ww] = kept64; s_totw[ww] = total; }
    }
    __syncthreads();
    const u64 kk = s_kept[ww];
    if (alive && w > ww && kk != 0ULL) {
      u64 t64 = kk;
      const int base = ww << 6;
      while (t64) {
        int b = __ffsll(t64) - 1;
        t64 &= t64 - 1ULL;
        int i = base + b;
        float ix1 = fmaxf(sx1[i], mx1), iy1 = fmaxf(sy1[i], my1);
        float ix2 = fminf(sx2[i], mx2), iy2 = fminf(sy2[i], my2);
        float iw = fmaxf(ix2 - ix1, 0.f), ih = fmaxf(iy2 - iy1, 0.f);
        float inter = iw * ih;
        float uni = sar[i] + mar - inter;
        if (inter / fmaxf(uni, 1e-9f) > NTHR) { alive = false; break; }
      }
    }
    finaltot = s_totw[ww];
    if (finaltot >= MDET) { capped = true; break; }
  }

  if (tid == 0)
    flags[c] = (!capped && finaltot < MDET && gc < min(M, PK)) ? 1 : 0;
}

// ---------------- exact fallback for flagged classes (never taken normally) ------
__device__ void fb_class(int c, const int* counts, const u64* cand,
                         const float4* boxes, u64* det, unsigned* aux, u64* lds) {
  const int tid = threadIdx.x;
  u64* sb = lds;                               // 4096 u64
  float* fx1 = (float*)(lds + 4096);
  float* fy1 = fx1 + PK; float* fx2 = fy1 + PK; float* fy2 = fx2 + PK; float* fa = fy2 + PK;
  unsigned char* al = (unsigned char*)(fa + PK);
  const int M = min(counts[c * CPAD], CMAX);
  int NS = PK;
  while (NS < M) NS <<= 1;
  for (int t = tid; t < NS; t += 1024) sb[t] = (t < M) ? cand[(size_t)c * CMAX + t] : 0ULL;
  bitonic_desc(sb, NS, tid, 1024);
  const int Mk = min(M, PK);
  if (tid < Mk) {
    u64 k = sb[tid];
    unsigned aidx = 0xFFFFFFFFu - (unsigned)(k & 0xFFFFFFFFull);
    float4 b = boxes[aidx];
    fx1[tid] = b.x; fy1[tid] = b.y; fx2[tid] = b.z; fy2[tid] = b.w;
    fa[tid] = (b.z - b.x) * (b.w - b.y);
  }
  if (tid < PK) al[tid] = (tid < Mk) ? 1 : 0;
  __syncthreads();
  if (tid < 64) {                              // wave-serial greedy, O(M) per kept
    int kept = 0;
    for (int i = 0; i < Mk && kept < MDET; ++i) {
      if (!al[i]) continue;
      if (tid == 0) {
        u64 key = sb[i];
        int idx = c * MDET + kept;
        det[idx] = (key & 0xFFFFFFFF00000000ull) | (u64)(0xFFFFFFFFu - (unsigned)idx);
        aux[idx] = 0xFFFFFFFFu - (unsigned)(key & 0xFFFFFFFFull);
      }
      float x1 = fx1[i], y1 = fy1[i], x2 = fx2[i], y2 = fy2[i], ai = fa[i];
      for (int j = i + 1 + tid; j < Mk; j += 64) {
        float ix1 = fmaxf(x1, fx1[j]), iy1 = fmaxf(y1, fy1[j]);
        float ix2 = fminf(x2, fx2[j]), iy2 = fminf(y2, fy2[j]);
        float iw = fmaxf(ix2 - ix1, 0.f), ih = fmaxf(iy2 - iy1, 0.f);
        float inter = iw * ih;
        float uni = ai + fa[j] - inter;
        if (inter / fmaxf(uni, 1e-9f) > NTHR) al[j] = 0;
      }
      ++kept;
    }
  }
  __syncthreads();
}

// ---------------- global top-100: stage 9000 keys -> radix-select -> wave sort ----
__global__ __launch_bounds__(1024) void k_final(const int* __restrict__ flags,
                                                const int* __restrict__ counts,
                                                const u64* __restrict__ cand,
                                                const u64* __restrict__ det,
                                                const unsigned* __restrict__ aux,
                                                const float4* __restrict__ boxes,
                                                const float* __restrict__ rot,
                                                const float* __restrict__ trn,
                                                float* __restrict__ out) {
  extern __shared__ u64 dyn2[];                 // 90112 B
  u64* D = dyn2;                                // 9216 u64 (keys; also fb scratch)
  unsigned* hist = (unsigned*)(D + 9216);       // 2048 u32 (NBF used)
  u64* sel = (u64*)(hist + 2048);               // 1024 u64
  __shared__ unsigned wsum[16], wsuf[16];
  __shared__ int s_B, s_gc, s_gcnt, s_any;

  const int tid = threadIdx.x;
  const int wave = tid >> 6;
  const int lane = tid & 63;
  const unsigned SB = __float_as_uint(STHR);
  const int NTOT = NC * MDET;                   // 9000

  if (tid == 0) { s_any = 0; s_gcnt = 0; }
  __syncthreads();
  if (tid < NC && flags[tid] != 0) s_any = 1;
  __syncthreads();
  if (s_any) {                                  // exact re-do of flagged classes
    for (int c = 0; c < NC; ++c)
      if (flags[c]) fb_class(c, counts, cand, boxes, (u64*)det, (unsigned*)aux, dyn2);
    __threadfence();
    __syncthreads();
  }

  for (int t = tid; t < 9216; t += 1024) D[t] = (t < NTOT) ? det[t] : 0ULL;
  for (int t = tid; t < 2048; t += 1024) hist[t] = 0u;
  sel[tid] = 0ULL;
  __syncthreads();

  for (int t = tid; t < NTOT; t += 1024) {
    u64 k = D[t];
    if (k) atomicAdd(&hist[binf((unsigned)(k >> 32), SB)], 1u);
  }
  __syncthreads();

  // hierarchical suffix scan over NBF bins -> threshold bin B with suffix >= MDET
  const int CH = (NBF + 1023) >> 10;
  int clo = tid * CH, chi = min(clo + CH, NBF);
  unsigned s = 0;
  for (int bb = clo; bb < chi; ++bb) s += hist[bb];
  unsigned ss = s;
  for (int d = 1; d < 64; d <<= 1) {
    unsigned v = __shfl_down(ss, d);
    if (lane + d < 64) ss += v;
  }
  if (lane == 0) wsum[wave] = ss;
  __syncthreads();
  if (tid < 16) {
    unsigned t = wsum[tid];
    for (int d = 1; d < 16; d <<= 1) {
      unsigned v = __shfl_down(t, d);
      if (tid + d < 16) t += v;
    }
    wsuf[tid] = t;
  }
  __syncthreads();
  unsigned suff = ss + ((wave < 15) ? wsuf[wave + 1] : 0u);
  unsigned suffn = suff - s;
  if (tid == 0 && wsuf[0] < MDET) { s_B = 0; s_gc = (int)wsuf[0]; }
  if (suff >= MDET && suffn < MDET) {
    unsigned after = suffn;
    int Bf = clo;
    for (int bb = chi - 1; bb >= clo; --bb) {
      after += hist[bb];
      if (after >= MDET) { Bf = bb; break; }
    }
    s_B = Bf; s_gc = (int)after;
  }
  __syncthreads();
  const int B = s_B, gc = s_gc;

  for (int t = tid; t < NTOT; t += 1024) {
    u64 k = D[t];
    if (k && binf((unsigned)(k >> 32), SB) >= B) {
      int p = atomicAdd(&s_gcnt, 1);
      if (p < 1024) sel[p] = k;
    }
  }
  __syncthreads();

  if (gc <= 128) {
    // single-wave 128-sort: 2 regs/lane, no barriers
    if (tid < 64) {
      u64 ea = sel[lane], eb = sel[64 + lane];
      auto CSWL = [&](u64& lo, u64& hi, int ilow, int k) {
        bool tml = ((ilow & k) == 0);
        u64 mx = lo >= hi ? lo : hi, mn = lo >= hi ? hi : lo;
        lo = tml ? mx : mn; hi = tml ? mn : mx;
      };
      auto SH = [&](u64& x, int ibase, int j, int k) {
        u64 p = __shfl_xor(x, j, 64);
        bool tm = ((((ibase | lane) & k) == 0) != ((lane & j) != 0));
        u64 mx = x >= p ? x : p, mn = x >= p ? p : x;
        x = tm ? mx : mn;
      };
      for (int k = 2; k <= 128; k <<= 1) {
        for (int j = k >> 1; j > 0; j >>= 1) {
          if (j == 64) CSWL(ea, eb, lane, k);
          else { SH(ea, 0, j, k); SH(eb, 64, j, k); }
        }
      }
      sel[lane] = ea; sel[64 + lane] = eb;
    }
    __syncthreads();
  } else {
    int NSf = 128;
    while (NSf < gc && NSf < 1024) NSf <<= 1;
    bitonic_desc(sel, NSf, tid, 1024);
  }

  // gather top-100 outputs
  if (tid < MDET) {
    u64 key = sel[tid];
    bool ok = (key != 0ULL);
    float b0 = -1.f, b1 = -1.f, b2 = -1.f, b3 = -1.f;
    float r0 = -1.f, r1 = -1.f, r2 = -1.f;
    float t0 = -1.f, t1 = -1.f, t2 = -1.f;
    float sc = -1.f, lab = -1.f;
    if (ok) {
      float score = __uint_as_float((unsigned)(key >> 32));
      unsigned idx = 0xFFFFFFFFu - (unsigned)(key & 0xFFFFFFFFull);
      int c = idx / MDET;
      unsigned aidx = aux[idx];
      float4 bb = boxes[aidx];
      b0 = bb.x; b1 = bb.y; b2 = bb.z; b3 = bb.w;
      sc = score; lab = (float)c;
      r0 = rot[aidx*3+0]; r1 = rot[aidx*3+1]; r2 = rot[aidx*3+2];
      t0 = trn[aidx*3+0]; t1 = trn[aidx*3+1]; t2 = trn[aidx*3+2];
    }
    out[tid*4+0] = b0; out[tid*4+1] = b1; out[tid*4+2] = b2; out[tid*4+3] = b3;
    out[400 + tid] = sc;
    out[500 + tid] = lab;
    out[600 + tid*3+0] = r0; out[600 + tid*3+1] = r1; out[600 + tid*3+2] = r2;
    out[900 + tid*3+0] = t0; out[900 + tid*3+1] = t1; out[900 + tid*3+2] = t2;
  }
}

extern "C" void kernel_launch(void* const* d_in, const int* in_sizes, int n_in,
                              void* d_out, int out_size, void* d_ws, size_t ws_size,
                              hipStream_t stream) {
  const float* anchors        = (const float*)d_in[0];
  const float* regression     = (const float*)d_in[1];
  const float* classification = (const float*)d_in[2];
  const float* rotation       = (const float*)d_in[3];
  const float* tanch          = (const float*)d_in[4];
  const float* tdelta         = (const float*)d_in[5];
  float* out = (float*)d_out;

  char* ws = (char*)d_ws;
  size_t off = 0;
  auto alloc = [&](size_t bytes) -> void* {
    void* p = ws + off;
    off += (bytes + 255) & ~(size_t)255;
    return p;
  };
  float*    boxes  = (float*)alloc((size_t)NA * 4 * 4);
  float*    trn    = (float*)alloc((size_t)NA * 3 * 4);
  int*      counts = (int*)alloc(NC * CPAD * 4);
  int*      histc  = (int*)alloc(NC * NBC * 4);
  u64*      cand   = (u64*)alloc((size_t)NC * CMAX * 8);
  u64*      det    = (u64*)alloc((size_t)NC * MDET * 8);
  unsigned* aux    = (unsigned*)alloc((size_t)NC * MDET * 4);
  int*      flags  = (int*)alloc(NC * 4);

  k_decode<<<(NA + 255) / 256, 256, 0, stream>>>(
      (const float4*)anchors, (const float4*)regression, tanch, tdelta,
      (float4*)boxes, trn, counts, histc);
  k_collect<<<2048, 256, 0, stream>>>((const float4*)classification, counts, cand, histc);
  k_classnms<<<NC, 256, 0, stream>>>(counts, cand, histc, (const float4*)boxes,
                                     det, aux, flags);

  hipFuncSetAttribute(reinterpret_cast<const void*>(k_final),
                      hipFuncAttributeMaxDynamicSharedMemorySize, 90112);
  k_final<<<1, 1024, 90112, stream>>>(flags, counts, cand, det, aux,
                                      (const float4*)boxes, rotation, trn, out);
}

// Round 9
// 73.403 us; speedup vs baseline: 10.7267x; 1.1836x over previous
//
#include <hip/hip_runtime.h>

#define NA 150381
#define NC 90
#define PK 1024
#define CMAX 4096
#define MDET 100
#define STHR 0.996f
#define NTHR 0.5f
#define IMGF 896.0f
#define CPAD 32    // counts padded: one 128B cacheline per class
#define NBC 264    // per-class selection histogram bins (span>>8, padded)
#define NBF 1056   // final top-100 histogram bins (span>>6, padded)
#define SELT 192   // per-class selection target (>= MDET + suppression slack)

typedef unsigned long long u64;

__device__ __forceinline__ int binc(unsigned bits, unsigned SB) {
  int b = (int)((bits - SB) >> 8);
  return b < NBC - 1 ? b : NBC - 1;
}
__device__ __forceinline__ int binf(unsigned bits, unsigned SB) {
  int b = (int)((bits - SB) >> 6);
  return b < NBF - 1 ? b : NBF - 1;
}
// single source of truth for box decode -> bit-identical everywhere
__device__ __forceinline__ float4 decode_box(float4 a, float4 r) {
  float cxa = (a.x + a.z) * 0.5f, cya = (a.y + a.w) * 0.5f;
  float wa = a.z - a.x, ha = a.w - a.y;
  float w = expf(r.w) * wa, h = expf(r.z) * ha;
  float cy = r.x * ha + cya, cx = r.y * wa + cxa;
  float4 b;
  b.x = fminf(fmaxf(cx - w * 0.5f, 0.f), IMGF);
  b.y = fminf(fmaxf(cy - h * 0.5f, 0.f), IMGF);
  b.z = fminf(fmaxf(cx + w * 0.5f, 0.f), IMGF);
  b.w = fminf(fmaxf(cy + h * 0.5f, 0.f), IMGF);
  return b;
}

// ---------------- threshold filter into per-class lists + class histograms ------
__global__ void k_collect(const float4* __restrict__ cls4, int* __restrict__ counts,
                          u64* __restrict__ cand, int* __restrict__ histc) {
  const unsigned SB = __float_as_uint(STHR);
  const int total = NA * NC;
  const int nv4 = total >> 2;
  const int stride = gridDim.x * blockDim.x;
  for (int q = blockIdx.x * blockDim.x + threadIdx.x; q < nv4; q += stride) {
    float4 v4 = cls4[q];
    float vv[4] = {v4.x, v4.y, v4.z, v4.w};
    #pragma unroll
    for (int e = 0; e < 4; ++e) {
      float v = vv[e];
      if (v > STHR) {
        int f = q * 4 + e;
        int c = f % NC;
        int i = f / NC;
        unsigned bits = __float_as_uint(v);
        int pos = atomicAdd(&counts[c * CPAD], 1);
        if (pos < CMAX)
          cand[(size_t)c * CMAX + pos] =
              ((u64)bits << 32) | (u64)(0xFFFFFFFFu - (unsigned)i);
        atomicAdd(&histc[c * NBC + binc(bits, SB)], 1);
      }
    }
  }
  int g = blockIdx.x * blockDim.x + threadIdx.x;
  if (g < total - nv4 * 4) {
    int f = nv4 * 4 + g;
    float v = ((const float*)cls4)[f];
    if (v > STHR) {
      int c = f % NC;
      int i = f / NC;
      unsigned bits = __float_as_uint(v);
      int pos = atomicAdd(&counts[c * CPAD], 1);
      if (pos < CMAX)
        cand[(size_t)c * CMAX + pos] =
            ((u64)bits << 32) | (u64)(0xFFFFFFFFu - (unsigned)i);
      atomicAdd(&histc[c * NBC + binc(bits, SB)], 1);
    }
  }
}

__device__ __forceinline__ void bitonic_desc(u64* a, int n, int tid, int nth) {
  for (int k = 2; k <= n; k <<= 1) {
    for (int j = k >> 1; j > 0; j >>= 1) {
      __syncthreads();
      for (int i = tid; i < n; i += nth) {
        int ixj = i ^ j;
        if (ixj > i) {
          u64 x = a[i], y = a[ixj];
          if (((i & k) == 0) ? (x < y) : (x > y)) { a[i] = y; a[ixj] = x; }
        }
      }
    }
  }
  __syncthreads();
}

// ---------------- per-class: radix-select top~192 -> wave sort -> fixpoint NMS ----
// Greedy NMS computed as a ballot fixpoint over per-column suppression masks:
//   K_{n+1}(t) = [ colmask_t & K_n (bits < t only, by construction) == 0 ]
// Triangular dependence => unique fixpoint == greedy keep set; converges in
// suppression-chain-depth iterations (typ. 2-4), all in wave-0 registers.
__global__ __launch_bounds__(512) void k_classnms(const int* __restrict__ counts,
                                                  const u64* __restrict__ cand,
                                                  const int* __restrict__ histc,
                                                  const float4* __restrict__ anc,
                                                  const float4* __restrict__ reg,
                                                  u64* __restrict__ det,
                                                  unsigned* __restrict__ aux,
                                                  int* __restrict__ flags) {
  __shared__ u64 sel[256];
  __shared__ float sx1[256], sy1[256], sx2[256], sy2[256], sar[256];
  __shared__ u64 cm2[512][5];                    // [half*256+t][word], +1 pad
  __shared__ u64 s_K[4];
  __shared__ int s_B, s_gc, s_cnt;
  __shared__ int wsum[8], wsuf[8];
  const int c = blockIdx.x, tid = threadIdx.x;
  const unsigned SB = __float_as_uint(STHR);
  const int M = min(counts[c * CPAD], CMAX);

  if (tid < MDET) det[c * MDET + tid] = 0ULL;    // zero my det row first
  if (tid < 256) sel[tid] = 0ULL;
  if (tid == 0) s_cnt = 0;

  // ---- selection threshold: ONE global round, hierarchical suffix scan ----
  {
    const int b0 = 2 * tid;
    const int h0 = (b0 < NBC) ? histc[c * NBC + b0] : 0;
    const int h1 = (b0 + 1 < NBC) ? histc[c * NBC + b0 + 1] : 0;
    const int s = h0 + h1;
    const int lane = tid & 63, wv = tid >> 6;
    int ss = s;
    for (int d = 1; d < 64; d <<= 1) {
      int v = __shfl_down(ss, d);
      if (lane + d < 64) ss += v;
    }
    if (lane == 0) wsum[wv] = ss;
    __syncthreads();
    if (tid < 8) {
      int x = wsum[tid];
      for (int d = 1; d < 8; d <<= 1) {
        int v = __shfl_down(x, d);
        if (tid + d < 8) x += v;
      }
      wsuf[tid] = x;
    }
    __syncthreads();
    int suff = ss + ((wv < 7) ? wsuf[wv + 1] : 0);
    int suffn = suff - s;
    if (tid == 0 && wsuf[0] < SELT) { s_B = 0; s_gc = wsuf[0]; }
    if (suff >= SELT && suffn < SELT) {
      if (suffn + h1 >= SELT) { s_B = b0 + 1; s_gc = suffn + h1; }
      else { s_B = b0; s_gc = suff; }
    }
    __syncthreads();
  }
  const int B = s_B;
  const int gc = s_gc;
  if (gc > 256) {                                 // tie pileup: exact fallback
    if (tid == 0) flags[c] = 1;
    return;
  }

  // ---- gather selected candidates (strict score-bin prefix of sorted order) ----
  for (int t = tid; t < M; t += 512) {
    u64 k = cand[(size_t)c * CMAX + t];
    if (binc((unsigned)(k >> 32), SB) >= B) {
      int p = atomicAdd(&s_cnt, 1);
      if (p < 256) sel[p] = k;
    }
  }
  __syncthreads();

  // ---- sort 256 slots in ONE wave: 4 regs/lane, shfl + local swaps, no barriers ----
  if (tid < 64 && gc > 0) {
    const int l = tid;
    u64 ea = sel[l], eb = sel[64 + l], ec = sel[128 + l], ed = sel[192 + l];
    auto CSWL = [&](u64& lo, u64& hi, int ilow, int k) {
      bool tml = ((ilow & k) == 0);
      u64 mx = lo >= hi ? lo : hi, mn = lo >= hi ? hi : lo;
      lo = tml ? mx : mn; hi = tml ? mn : mx;
    };
    auto SH = [&](u64& x, int ibase, int j, int k) {
      u64 p = __shfl_xor(x, j, 64);
      bool tm = ((((ibase | l) & k) == 0) != ((l & j) != 0));
      u64 mx = x >= p ? x : p, mn = x >= p ? p : x;
      x = tm ? mx : mn;
    };
    for (int k = 2; k <= 256; k <<= 1) {
      for (int j = k >> 1; j > 0; j >>= 1) {
        if (j == 128)      { CSWL(ea, ec, l, k);       CSWL(eb, ed, 64 | l, k); }
        else if (j == 64)  { CSWL(ea, eb, l, k);       CSWL(ec, ed, 128 | l, k); }
        else { SH(ea, 0, j, k); SH(eb, 64, j, k); SH(ec, 128, j, k); SH(ed, 192, j, k); }
      }
    }
    sel[l] = ea; sel[64 + l] = eb; sel[128 + l] = ec; sel[192 + l] = ed;
  }
  __syncthreads();

  // ---- stage decoded boxes for ranks [0, gc) ----
  u64 myk = 0; unsigned myaidx = 0;
  if (tid < 256 && tid < gc) {
    myk = sel[tid];
    myaidx = 0xFFFFFFFFu - (unsigned)(myk & 0xFFFFFFFFull);
    float4 b = decode_box(anc[myaidx], reg[myaidx]);
    sx1[tid] = b.x; sy1[tid] = b.y; sx2[tid] = b.z; sy2[tid] = b.w;
    sar[tid] = (b.z - b.x) * (b.w - b.y);
  }
  __syncthreads();

  // ---- colmask build: 2 threads per column, fully parallel ----
  const int t = tid & 255, half = tid >> 8;
  u64 cw0 = 0, cw1 = 0, cw2 = 0, cw3 = 0;
  if (t < gc) {
    const float cx1 = sx1[t], cy1 = sy1[t], cx2 = sx2[t], cy2 = sy2[t], car = sar[t];
    for (int j = half; j < t; j += 2) {
      float ix1 = fmaxf(cx1, sx1[j]), iy1 = fmaxf(cy1, sy1[j]);
      float ix2 = fminf(cx2, sx2[j]), iy2 = fminf(cy2, sy2[j]);
      float iw = fmaxf(ix2 - ix1, 0.f), ih = fmaxf(iy2 - iy1, 0.f);
      float inter = iw * ih;
      float uni = car + sar[j] - inter;
      if (inter / fmaxf(uni, 1e-9f) > NTHR) {
        if (j < 64)       cw0 |= 1ULL << j;
        else if (j < 128) cw1 |= 1ULL << (j - 64);
        else if (j < 192) cw2 |= 1ULL << (j - 128);
        else              cw3 |= 1ULL << (j - 192);
      }
    }
  }
  cm2[tid][0] = cw0; cm2[tid][1] = cw1; cm2[tid][2] = cw2; cm2[tid][3] = cw3;
  __syncthreads();
  if (tid < 256) {
    cm2[tid][0] |= cm2[256 + tid][0];
    cm2[tid][1] |= cm2[256 + tid][1];
    cm2[tid][2] |= cm2[256 + tid][2];
    cm2[tid][3] |= cm2[256 + tid][3];
  }
  __syncthreads();

  // ---- ballot fixpoint in wave 0 (registers only, no barriers) ----
  if (tid < 64) {
    const int l = tid;
    u64 a00 = cm2[l][0],       a01 = cm2[l][1],       a02 = cm2[l][2],       a03 = cm2[l][3];
    u64 a10 = cm2[64 + l][0],  a11 = cm2[64 + l][1],  a12 = cm2[64 + l][2],  a13 = cm2[64 + l][3];
    u64 a20 = cm2[128 + l][0], a21 = cm2[128 + l][1], a22 = cm2[128 + l][2], a23 = cm2[128 + l][3];
    u64 a30 = cm2[192 + l][0], a31 = cm2[192 + l][1], a32 = cm2[192 + l][2], a33 = cm2[192 + l][3];
    u64 vm0 = (gc >= 64) ? ~0ULL : ((gc > 0) ? ((1ULL << gc) - 1) : 0ULL);
    u64 vm1 = (gc >= 128) ? ~0ULL : ((gc > 64) ? ((1ULL << (gc - 64)) - 1) : 0ULL);
    u64 vm2 = (gc >= 192) ? ~0ULL : ((gc > 128) ? ((1ULL << (gc - 128)) - 1) : 0ULL);
    u64 vm3 = (gc >= 256) ? ~0ULL : ((gc > 192) ? ((1ULL << (gc - 192)) - 1) : 0ULL);
    u64 K0 = vm0, K1 = vm1, K2 = vm2, K3 = vm3;
    for (int it = 0; it < 300; ++it) {
      bool al0 = ((a00 & K0) | (a01 & K1) | (a02 & K2) | (a03 & K3)) == 0ULL;
      bool al1 = ((a10 & K0) | (a11 & K1) | (a12 & K2) | (a13 & K3)) == 0ULL;
      bool al2 = ((a20 & K0) | (a21 & K1) | (a22 & K2) | (a23 & K3)) == 0ULL;
      bool al3 = ((a30 & K0) | (a31 & K1) | (a32 & K2) | (a33 & K3)) == 0ULL;
      u64 n0 = __ballot(al0) & vm0;
      u64 n1 = __ballot(al1) & vm1;
      u64 n2 = __ballot(al2) & vm2;
      u64 n3 = __ballot(al3) & vm3;
      bool same = (n0 == K0) && (n1 == K1) && (n2 == K2) && (n3 == K3);
      K0 = n0; K1 = n1; K2 = n2; K3 = n3;
      if (same) break;                            // fixpoint == greedy keep set
    }
    if (l == 0) { s_K[0] = K0; s_K[1] = K1; s_K[2] = K2; s_K[3] = K3; }
  }
  __syncthreads();

  // ---- slots via popcount; direct det/aux writes ----
  if (tid < 256 && tid < gc) {
    int g = tid >> 6;
    u64 kw = s_K[g];
    if ((kw >> (tid & 63)) & 1ULL) {
      int slot = __popcll(kw & ((1ULL << (tid & 63)) - 1ULL));
      for (int gg = 0; gg < g; ++gg) slot += __popcll(s_K[gg]);
      if (slot < MDET) {
        int idx = c * MDET + slot;
        det[idx] = (myk & 0xFFFFFFFF00000000ull) | (u64)(0xFFFFFFFFu - (unsigned)idx);
        aux[idx] = myaidx;
      }
    }
  }
  if (tid == 0) {
    int keptcnt = __popcll(s_K[0]) + __popcll(s_K[1]) + __popcll(s_K[2]) + __popcll(s_K[3]);
    flags[c] = (keptcnt < MDET && gc < min(M, PK)) ? 1 : 0;
  }
}

// ---------------- exact fallback for flagged classes (never taken normally) ------
__device__ void fb_class(int c, const int* counts, const u64* cand,
                         const float4* anc, const float4* reg,
                         u64* det, unsigned* aux, u64* lds) {
  const int tid = threadIdx.x;
  u64* sb = lds;                               // 4096 u64
  float* fx1 = (float*)(lds + 4096);
  float* fy1 = fx1 + PK; float* fx2 = fy1 + PK; float* fy2 = fx2 + PK; float* fa = fy2 + PK;
  unsigned char* al = (unsigned char*)(fa + PK);
  const int M = min(counts[c * CPAD], CMAX);
  int NS = PK;
  while (NS < M) NS <<= 1;
  for (int t = tid; t < NS; t += 1024) sb[t] = (t < M) ? cand[(size_t)c * CMAX + t] : 0ULL;
  bitonic_desc(sb, NS, tid, 1024);
  const int Mk = min(M, PK);
  if (tid < Mk) {
    u64 k = sb[tid];
    unsigned aidx = 0xFFFFFFFFu - (unsigned)(k & 0xFFFFFFFFull);
    float4 b = decode_box(anc[aidx], reg[aidx]);
    fx1[tid] = b.x; fy1[tid] = b.y; fx2[tid] = b.z; fy2[tid] = b.w;
    fa[tid] = (b.z - b.x) * (b.w - b.y);
  }
  if (tid < PK) al[tid] = (tid < Mk) ? 1 : 0;
  __syncthreads();
  if (tid < 64) {                              // wave-serial greedy, O(M) per kept
    int kept = 0;
    for (int i = 0; i < Mk && kept < MDET; ++i) {
      if (!al[i]) continue;
      if (tid == 0) {
        u64 key = sb[i];
        int idx = c * MDET + kept;
        det[idx] = (key & 0xFFFFFFFF00000000ull) | (u64)(0xFFFFFFFFu - (unsigned)idx);
        aux[idx] = 0xFFFFFFFFu - (unsigned)(key & 0xFFFFFFFFull);
      }
      float x1 = fx1[i], y1 = fy1[i], x2 = fx2[i], y2 = fy2[i], ai = fa[i];
      for (int j = i + 1 + tid; j < Mk; j += 64) {
        float ix1 = fmaxf(x1, fx1[j]), iy1 = fmaxf(y1, fy1[j]);
        float ix2 = fminf(x2, fx2[j]), iy2 = fminf(y2, fy2[j]);
        float iw = fmaxf(ix2 - ix1, 0.f), ih = fmaxf(iy2 - iy1, 0.f);
        float inter = iw * ih;
        float uni = ai + fa[j] - inter;
        if (inter / fmaxf(uni, 1e-9f) > NTHR) al[j] = 0;
      }
      ++kept;
    }
  }
  __syncthreads();
}

// ---------------- global top-100: stage 9000 keys -> radix-select -> wave sort ----
__global__ __launch_bounds__(1024) void k_final(const int* __restrict__ flags,
                                                const int* __restrict__ counts,
                                                const u64* __restrict__ cand,
                                                const u64* __restrict__ det,
                                                const unsigned* __restrict__ aux,
                                                const float4* __restrict__ anc,
                                                const float4* __restrict__ reg,
                                                const float* __restrict__ ta,
                                                const float* __restrict__ td,
                                                const float* __restrict__ rot,
                                                float* __restrict__ out) {
  extern __shared__ u64 dyn2[];                 // 90112 B
  u64* D = dyn2;                                // 9216 u64 (keys; also fb scratch)
  unsigned* hist = (unsigned*)(D + 9216);       // 2048 u32 (NBF used)
  u64* sel = (u64*)(hist + 2048);               // 1024 u64
  __shared__ unsigned wsum[16], wsuf[16];
  __shared__ int s_B, s_gc, s_gcnt, s_any;

  const int tid = threadIdx.x;
  const int wave = tid >> 6;
  const int lane = tid & 63;
  const unsigned SB = __float_as_uint(STHR);
  const int NTOT = NC * MDET;                   // 9000

  if (tid == 0) { s_any = 0; s_gcnt = 0; }
  __syncthreads();
  if (tid < NC && flags[tid] != 0) s_any = 1;
  __syncthreads();
  if (s_any) {                                  // exact re-do of flagged classes
    for (int c = 0; c < NC; ++c)
      if (flags[c]) fb_class(c, counts, cand, anc, reg, (u64*)det, (unsigned*)aux, dyn2);
    __threadfence();
    __syncthreads();
  }

  for (int t = tid; t < 9216; t += 1024) D[t] = (t < NTOT) ? det[t] : 0ULL;
  for (int t = tid; t < 2048; t += 1024) hist[t] = 0u;
  sel[tid] = 0ULL;
  __syncthreads();

  for (int t = tid; t < NTOT; t += 1024) {
    u64 k = D[t];
    if (k) atomicAdd(&hist[binf((unsigned)(k >> 32), SB)], 1u);
  }
  __syncthreads();

  // hierarchical suffix scan over NBF bins -> threshold bin B with suffix >= MDET
  const int CH = (NBF + 1023) >> 10;
  int clo = tid * CH, chi = min(clo + CH, NBF);
  unsigned s = 0;
  for (int bb = clo; bb < chi; ++bb) s += hist[bb];
  unsigned ss = s;
  for (int d = 1; d < 64; d <<= 1) {
    unsigned v = __shfl_down(ss, d);
    if (lane + d < 64) ss += v;
  }
  if (lane == 0) wsum[wave] = ss;
  __syncthreads();
  if (tid < 16) {
    unsigned t = wsum[tid];
    for (int d = 1; d < 16; d <<= 1) {
      unsigned v = __shfl_down(t, d);
      if (tid + d < 16) t += v;
    }
    wsuf[tid] = t;
  }
  __syncthreads();
  unsigned suff = ss + ((wave < 15) ? wsuf[wave + 1] : 0u);
  unsigned suffn = suff - s;
  if (tid == 0 && wsuf[0] < MDET) { s_B = 0; s_gc = (int)wsuf[0]; }
  if (suff >= MDET && suffn < MDET) {
    unsigned after = suffn;
    int Bf = clo;
    for (int bb = chi - 1; bb >= clo; --bb) {
      after += hist[bb];
      if (after >= MDET) { Bf = bb; break; }
    }
    s_B = Bf; s_gc = (int)after;
  }
  __syncthreads();
  const int B = s_B, gc = s_gc;

  for (int t = tid; t < NTOT; t += 1024) {
    u64 k = D[t];
    if (k && binf((unsigned)(k >> 32), SB) >= B) {
      int p = atomicAdd(&s_gcnt, 1);
      if (p < 1024) sel[p] = k;
    }
  }
  __syncthreads();

  if (gc <= 128) {
    // single-wave 128-sort: 2 regs/lane, no barriers
    if (tid < 64) {
      u64 ea = sel[lane], eb = sel[64 + lane];
      auto CSWL = [&](u64& lo, u64& hi, int ilow, int k) {
        bool tml = ((ilow & k) == 0);
        u64 mx = lo >= hi ? lo : hi, mn = lo >= hi ? hi : lo;
        lo = tml ? mx : mn; hi = tml ? mn : mx;
      };
      auto SH = [&](u64& x, int ibase, int j, int k) {
        u64 p = __shfl_xor(x, j, 64);
        bool tm = ((((ibase | lane) & k) == 0) != ((lane & j) != 0));
        u64 mx = x >= p ? x : p, mn = x >= p ? p : x;
        x = tm ? mx : mn;
      };
      for (int k = 2; k <= 128; k <<= 1) {
        for (int j = k >> 1; j > 0; j >>= 1) {
          if (j == 64) CSWL(ea, eb, lane, k);
          else { SH(ea, 0, j, k); SH(eb, 64, j, k); }
        }
      }
      sel[lane] = ea; sel[64 + lane] = eb;
    }
    __syncthreads();
  } else {
    int NSf = 128;
    while (NSf < gc && NSf < 1024) NSf <<= 1;
    bitonic_desc(sel, NSf, tid, 1024);
  }

  // gather top-100 outputs (decode box/translation on the fly)
  if (tid < MDET) {
    u64 key = sel[tid];
    bool ok = (key != 0ULL);
    float b0 = -1.f, b1 = -1.f, b2 = -1.f, b3 = -1.f;
    float r0 = -1.f, r1 = -1.f, r2 = -1.f;
    float t0 = -1.f, t1 = -1.f, t2 = -1.f;
    float sc = -1.f, lab = -1.f;
    if (ok) {
      float score = __uint_as_float((unsigned)(key >> 32));
      unsigned idx = 0xFFFFFFFFu - (unsigned)(key & 0xFFFFFFFFull);
      int c = idx / MDET;
      unsigned aidx = aux[idx];
      float4 bb = decode_box(anc[aidx], reg[aidx]);
      b0 = bb.x; b1 = bb.y; b2 = bb.z; b3 = bb.w;
      sc = score; lab = (float)c;
      r0 = rot[aidx*3+0]; r1 = rot[aidx*3+1]; r2 = rot[aidx*3+2];
      float st = ta[aidx*3+2];
      t0 = ta[aidx*3+0] + td[aidx*3+0] * st;
      t1 = ta[aidx*3+1] + td[aidx*3+1] * st;
      t2 = td[aidx*3+2];
    }
    out[tid*4+0] = b0; out[tid*4+1] = b1; out[tid*4+2] = b2; out[tid*4+3] = b3;
    out[400 + tid] = sc;
    out[500 + tid] = lab;
    out[600 + tid*3+0] = r0; out[600 + tid*3+1] = r1; out[600 + tid*3+2] = r2;
    out[900 + tid*3+0] = t0; out[900 + tid*3+1] = t1; out[900 + tid*3+2] = t2;
  }
}

extern "C" void kernel_launch(void* const* d_in, const int* in_sizes, int n_in,
                              void* d_out, int out_size, void* d_ws, size_t ws_size,
                              hipStream_t stream) {
  const float* anchors        = (const float*)d_in[0];
  const float* regression     = (const float*)d_in[1];
  const float* classification = (const float*)d_in[2];
  const float* rotation       = (const float*)d_in[3];
  const float* tanch          = (const float*)d_in[4];
  const float* tdelta         = (const float*)d_in[5];
  float* out = (float*)d_out;

  char* ws = (char*)d_ws;
  size_t off = 0;
  auto alloc = [&](size_t bytes) -> void* {
    void* p = ws + off;
    off += (bytes + 255) & ~(size_t)255;
    return p;
  };
  int*      counts = (int*)alloc(NC * CPAD * 4);       // 11520 B (256-aligned)
  int*      histc  = (int*)alloc(NC * NBC * 4);        // contiguous after counts
  u64*      cand   = (u64*)alloc((size_t)NC * CMAX * 8);
  u64*      det    = (u64*)alloc((size_t)NC * MDET * 8);
  unsigned* aux    = (unsigned*)alloc((size_t)NC * MDET * 4);
  int*      flags  = (int*)alloc(NC * 4);

  // one memset covers counts + histc (contiguous, counts size is 256-multiple)
  hipMemsetAsync(counts, 0, NC * CPAD * 4 + NC * NBC * 4, stream);

  k_collect<<<2048, 256, 0, stream>>>((const float4*)classification, counts, cand, histc);
  k_classnms<<<NC, 512, 0, stream>>>(counts, cand, histc,
                                     (const float4*)anchors, (const float4*)regression,
                                     det, aux, flags);

  hipFuncSetAttribute(reinterpret_cast<const void*>(k_final),
                      hipFuncAttributeMaxDynamicSharedMemorySize, 90112);
  k_final<<<1, 1024, 90112, stream>>>(flags, counts, cand, det, aux,
                                      (const float4*)anchors, (const float4*)regression,
                                      tanch, tdelta, rotation, out);
}

// Round 10
// 72.328 us; speedup vs baseline: 10.8861x; 1.0149x over previous
//
#include <hip/hip_runtime.h>

#define NA 150381
#define NC 90
#define PK 1024
#define CMAX 4096
#define MDET 100
#define STHR 0.996f
#define NTHR 0.5f
#define IMGF 896.0f
#define CPAD 32    // counts padded: one 128B cacheline per class
#define NBC 264    // per-class selection histogram bins (span>>8, padded)
#define NBF 1056   // final top-100 histogram bins (span>>6, padded)
#define SELT 192   // per-class selection target (>= MDET + suppression slack)

typedef unsigned long long u64;

__device__ __forceinline__ int binc(unsigned bits, unsigned SB) {
  int b = (int)((bits - SB) >> 8);
  return b < NBC - 1 ? b : NBC - 1;
}
__device__ __forceinline__ int binf(unsigned bits, unsigned SB) {
  int b = (int)((bits - SB) >> 6);
  return b < NBF - 1 ? b : NBF - 1;
}
// single source of truth for box decode -> bit-identical everywhere
__device__ __forceinline__ float4 decode_box(float4 a, float4 r) {
  float cxa = (a.x + a.z) * 0.5f, cya = (a.y + a.w) * 0.5f;
  float wa = a.z - a.x, ha = a.w - a.y;
  float w = expf(r.w) * wa, h = expf(r.z) * ha;
  float cy = r.x * ha + cya, cx = r.y * wa + cxa;
  float4 b;
  b.x = fminf(fmaxf(cx - w * 0.5f, 0.f), IMGF);
  b.y = fminf(fmaxf(cy - h * 0.5f, 0.f), IMGF);
  b.z = fminf(fmaxf(cx + w * 0.5f, 0.f), IMGF);
  b.w = fminf(fmaxf(cy + h * 0.5f, 0.f), IMGF);
  return b;
}

// ---------------- zero the per-class counters (replaces pathological runtime fill) --
__global__ void k_zero(int* __restrict__ counts) {
  int i = blockIdx.x * blockDim.x + threadIdx.x;
  if (i < NC * CPAD) counts[i] = 0;
}

// ---------------- threshold filter into per-class candidate lists ----------------
__global__ void k_collect(const float4* __restrict__ cls4, int* __restrict__ counts,
                          u64* __restrict__ cand) {
  const int total = NA * NC;
  const int nv4 = total >> 2;
  const int stride = gridDim.x * blockDim.x;
  for (int q = blockIdx.x * blockDim.x + threadIdx.x; q < nv4; q += stride) {
    float4 v4 = cls4[q];
    float vv[4] = {v4.x, v4.y, v4.z, v4.w};
    #pragma unroll
    for (int e = 0; e < 4; ++e) {
      float v = vv[e];
      if (v > STHR) {
        int f = q * 4 + e;
        int c = f % NC;
        int i = f / NC;
        int pos = atomicAdd(&counts[c * CPAD], 1);
        if (pos < CMAX)
          cand[(size_t)c * CMAX + pos] =
              ((u64)__float_as_uint(v) << 32) | (u64)(0xFFFFFFFFu - (unsigned)i);
      }
    }
  }
  int g = blockIdx.x * blockDim.x + threadIdx.x;
  if (g < total - nv4 * 4) {
    int f = nv4 * 4 + g;
    float v = ((const float*)cls4)[f];
    if (v > STHR) {
      int c = f % NC;
      int i = f / NC;
      int pos = atomicAdd(&counts[c * CPAD], 1);
      if (pos < CMAX)
        cand[(size_t)c * CMAX + pos] =
            ((u64)__float_as_uint(v) << 32) | (u64)(0xFFFFFFFFu - (unsigned)i);
    }
  }
}

__device__ __forceinline__ void bitonic_desc(u64* a, int n, int tid, int nth) {
  for (int k = 2; k <= n; k <<= 1) {
    for (int j = k >> 1; j > 0; j >>= 1) {
      __syncthreads();
      for (int i = tid; i < n; i += nth) {
        int ixj = i ^ j;
        if (ixj > i) {
          u64 x = a[i], y = a[ixj];
          if (((i & k) == 0) ? (x < y) : (x > y)) { a[i] = y; a[ixj] = x; }
        }
      }
    }
  }
  __syncthreads();
}

// ---------------- per-class: LDS hist select -> wave sort -> fixpoint NMS ----
// Greedy NMS as a ballot fixpoint over per-column suppression masks (unique
// fixpoint == greedy keep set; converges in chain-depth iters, registers only).
__global__ __launch_bounds__(512) void k_classnms(const int* __restrict__ counts,
                                                  const u64* __restrict__ cand,
                                                  const float4* __restrict__ anc,
                                                  const float4* __restrict__ reg,
                                                  u64* __restrict__ det,
                                                  unsigned* __restrict__ aux,
                                                  int* __restrict__ flags) {
  __shared__ u64 sel[256];
  __shared__ float sx1[256], sy1[256], sx2[256], sy2[256], sar[256];
  __shared__ u64 cm2[512][5];                    // [half*256+t][word], +1 pad
  __shared__ u64 s_K[4];
  __shared__ int lhist[NBC];
  __shared__ int s_B, s_gc, s_cnt;
  __shared__ int wsum[8], wsuf[8];
  const int c = blockIdx.x, tid = threadIdx.x;
  const unsigned SB = __float_as_uint(STHR);
  const int M = min(counts[c * CPAD], CMAX);

  if (tid < MDET) det[c * MDET + tid] = 0ULL;    // zero my det row first
  if (tid < 256) sel[tid] = 0ULL;
  if (tid == 0) s_cnt = 0;
  for (int t = tid; t < NBC; t += 512) lhist[t] = 0;
  __syncthreads();

  // ---- selection histogram in LDS from the class cand list ----
  for (int t = tid; t < M; t += 512) {
    u64 k = cand[(size_t)c * CMAX + t];
    atomicAdd(&lhist[binc((unsigned)(k >> 32), SB)], 1);
  }
  __syncthreads();

  // ---- threshold: hierarchical suffix scan over LDS hist ----
  {
    const int b0 = 2 * tid;
    const int h0 = (b0 < NBC) ? lhist[b0] : 0;
    const int h1 = (b0 + 1 < NBC) ? lhist[b0 + 1] : 0;
    const int s = h0 + h1;
    const int lane = tid & 63, wv = tid >> 6;
    int ss = s;
    for (int d = 1; d < 64; d <<= 1) {
      int v = __shfl_down(ss, d);
      if (lane + d < 64) ss += v;
    }
    if (lane == 0) wsum[wv] = ss;
    __syncthreads();
    if (tid < 8) {
      int x = wsum[tid];
      for (int d = 1; d < 8; d <<= 1) {
        int v = __shfl_down(x, d);
        if (tid + d < 8) x += v;
      }
      wsuf[tid] = x;
    }
    __syncthreads();
    int suff = ss + ((wv < 7) ? wsuf[wv + 1] : 0);
    int suffn = suff - s;
    if (tid == 0 && wsuf[0] < SELT) { s_B = 0; s_gc = wsuf[0]; }
    if (suff >= SELT && suffn < SELT) {
      if (suffn + h1 >= SELT) { s_B = b0 + 1; s_gc = suffn + h1; }
      else { s_B = b0; s_gc = suff; }
    }
    __syncthreads();
  }
  const int B = s_B;
  const int gc = s_gc;
  if (gc > 256) {                                 // tie pileup: exact fallback
    if (tid == 0) flags[c] = 1;
    return;
  }

  // ---- gather selected candidates (strict score-bin prefix of sorted order) ----
  for (int t = tid; t < M; t += 512) {
    u64 k = cand[(size_t)c * CMAX + t];
    if (binc((unsigned)(k >> 32), SB) >= B) {
      int p = atomicAdd(&s_cnt, 1);
      if (p < 256) sel[p] = k;
    }
  }
  __syncthreads();

  // ---- sort 256 slots in ONE wave: 4 regs/lane, shfl + local swaps, no barriers ----
  if (tid < 64 && gc > 0) {
    const int l = tid;
    u64 ea = sel[l], eb = sel[64 + l], ec = sel[128 + l], ed = sel[192 + l];
    auto CSWL = [&](u64& lo, u64& hi, int ilow, int k) {
      bool tml = ((ilow & k) == 0);
      u64 mx = lo >= hi ? lo : hi, mn = lo >= hi ? hi : lo;
      lo = tml ? mx : mn; hi = tml ? mn : mx;
    };
    auto SH = [&](u64& x, int ibase, int j, int k) {
      u64 p = __shfl_xor(x, j, 64);
      bool tm = ((((ibase | l) & k) == 0) != ((l & j) != 0));
      u64 mx = x >= p ? x : p, mn = x >= p ? p : x;
      x = tm ? mx : mn;
    };
    for (int k = 2; k <= 256; k <<= 1) {
      for (int j = k >> 1; j > 0; j >>= 1) {
        if (j == 128)      { CSWL(ea, ec, l, k);       CSWL(eb, ed, 64 | l, k); }
        else if (j == 64)  { CSWL(ea, eb, l, k);       CSWL(ec, ed, 128 | l, k); }
        else { SH(ea, 0, j, k); SH(eb, 64, j, k); SH(ec, 128, j, k); SH(ed, 192, j, k); }
      }
    }
    sel[l] = ea; sel[64 + l] = eb; sel[128 + l] = ec; sel[192 + l] = ed;
  }
  __syncthreads();

  // ---- stage decoded boxes for ranks [0, gc) ----
  u64 myk = 0; unsigned myaidx = 0;
  if (tid < 256 && tid < gc) {
    myk = sel[tid];
    myaidx = 0xFFFFFFFFu - (unsigned)(myk & 0xFFFFFFFFull);
    float4 b = decode_box(anc[myaidx], reg[myaidx]);
    sx1[tid] = b.x; sy1[tid] = b.y; sx2[tid] = b.z; sy2[tid] = b.w;
    sar[tid] = (b.z - b.x) * (b.w - b.y);
  }
  __syncthreads();

  // ---- colmask build: 2 threads per column, fully parallel ----
  const int t = tid & 255, half = tid >> 8;
  u64 cw0 = 0, cw1 = 0, cw2 = 0, cw3 = 0;
  if (t < gc) {
    const float cx1 = sx1[t], cy1 = sy1[t], cx2 = sx2[t], cy2 = sy2[t], car = sar[t];
    for (int j = half; j < t; j += 2) {
      float ix1 = fmaxf(cx1, sx1[j]), iy1 = fmaxf(cy1, sy1[j]);
      float ix2 = fminf(cx2, sx2[j]), iy2 = fminf(cy2, sy2[j]);
      float iw = fmaxf(ix2 - ix1, 0.f), ih = fmaxf(iy2 - iy1, 0.f);
      float inter = iw * ih;
      float uni = car + sar[j] - inter;
      if (inter / fmaxf(uni, 1e-9f) > NTHR) {
        if (j < 64)       cw0 |= 1ULL << j;
        else if (j < 128) cw1 |= 1ULL << (j - 64);
        else if (j < 192) cw2 |= 1ULL << (j - 128);
        else              cw3 |= 1ULL << (j - 192);
      }
    }
  }
  cm2[tid][0] = cw0; cm2[tid][1] = cw1; cm2[tid][2] = cw2; cm2[tid][3] = cw3;
  __syncthreads();
  if (tid < 256) {
    cm2[tid][0] |= cm2[256 + tid][0];
    cm2[tid][1] |= cm2[256 + tid][1];
    cm2[tid][2] |= cm2[256 + tid][2];
    cm2[tid][3] |= cm2[256 + tid][3];
  }
  __syncthreads();

  // ---- ballot fixpoint in wave 0 (registers only, no barriers) ----
  if (tid < 64) {
    const int l = tid;
    u64 a00 = cm2[l][0],       a01 = cm2[l][1],       a02 = cm2[l][2],       a03 = cm2[l][3];
    u64 a10 = cm2[64 + l][0],  a11 = cm2[64 + l][1],  a12 = cm2[64 + l][2],  a13 = cm2[64 + l][3];
    u64 a20 = cm2[128 + l][0], a21 = cm2[128 + l][1], a22 = cm2[128 + l][2], a23 = cm2[128 + l][3];
    u64 a30 = cm2[192 + l][0], a31 = cm2[192 + l][1], a32 = cm2[192 + l][2], a33 = cm2[192 + l][3];
    u64 vm0 = (gc >= 64) ? ~0ULL : ((gc > 0) ? ((1ULL << gc) - 1) : 0ULL);
    u64 vm1 = (gc >= 128) ? ~0ULL : ((gc > 64) ? ((1ULL << (gc - 64)) - 1) : 0ULL);
    u64 vm2 = (gc >= 192) ? ~0ULL : ((gc > 128) ? ((1ULL << (gc - 128)) - 1) : 0ULL);
    u64 vm3 = (gc >= 256) ? ~0ULL : ((gc > 192) ? ((1ULL << (gc - 192)) - 1) : 0ULL);
    u64 K0 = vm0, K1 = vm1, K2 = vm2, K3 = vm3;
    for (int it = 0; it < 300; ++it) {
      bool al0 = ((a00 & K0) | (a01 & K1) | (a02 & K2) | (a03 & K3)) == 0ULL;
      bool al1 = ((a10 & K0) | (a11 & K1) | (a12 & K2) | (a13 & K3)) == 0ULL;
      bool al2 = ((a20 & K0) | (a21 & K1) | (a22 & K2) | (a23 & K3)) == 0ULL;
      bool al3 = ((a30 & K0) | (a31 & K1) | (a32 & K2) | (a33 & K3)) == 0ULL;
      u64 n0 = __ballot(al0) & vm0;
      u64 n1 = __ballot(al1) & vm1;
      u64 n2 = __ballot(al2) & vm2;
      u64 n3 = __ballot(al3) & vm3;
      bool same = (n0 == K0) && (n1 == K1) && (n2 == K2) && (n3 == K3);
      K0 = n0; K1 = n1; K2 = n2; K3 = n3;
      if (same) break;                            // fixpoint == greedy keep set
    }
    if (l == 0) { s_K[0] = K0; s_K[1] = K1; s_K[2] = K2; s_K[3] = K3; }
  }
  __syncthreads();

  // ---- slots via popcount; direct det/aux writes ----
  if (tid < 256 && tid < gc) {
    int g = tid >> 6;
    u64 kw = s_K[g];
    if ((kw >> (tid & 63)) & 1ULL) {
      int slot = __popcll(kw & ((1ULL << (tid & 63)) - 1ULL));
      for (int gg = 0; gg < g; ++gg) slot += __popcll(s_K[gg]);
      if (slot < MDET) {
        int idx = c * MDET + slot;
        det[idx] = (myk & 0xFFFFFFFF00000000ull) | (u64)(0xFFFFFFFFu - (unsigned)idx);
        aux[idx] = myaidx;
      }
    }
  }
  if (tid == 0) {
    int keptcnt = __popcll(s_K[0]) + __popcll(s_K[1]) + __popcll(s_K[2]) + __popcll(s_K[3]);
    flags[c] = (keptcnt < MDET && gc < min(M, PK)) ? 1 : 0;
  }
}

// ---------------- exact fallback for flagged classes (never taken normally) ------
__device__ void fb_class(int c, const int* counts, const u64* cand,
                         const float4* anc, const float4* reg,
                         u64* det, unsigned* aux, u64* lds) {
  const int tid = threadIdx.x;
  u64* sb = lds;                               // 4096 u64
  float* fx1 = (float*)(lds + 4096);
  float* fy1 = fx1 + PK; float* fx2 = fy1 + PK; float* fy2 = fx2 + PK; float* fa = fy2 + PK;
  unsigned char* al = (unsigned char*)(fa + PK);
  const int M = min(counts[c * CPAD], CMAX);
  int NS = PK;
  while (NS < M) NS <<= 1;
  for (int t = tid; t < NS; t += 1024) sb[t] = (t < M) ? cand[(size_t)c * CMAX + t] : 0ULL;
  bitonic_desc(sb, NS, tid, 1024);
  const int Mk = min(M, PK);
  if (tid < Mk) {
    u64 k = sb[tid];
    unsigned aidx = 0xFFFFFFFFu - (unsigned)(k & 0xFFFFFFFFull);
    float4 b = decode_box(anc[aidx], reg[aidx]);
    fx1[tid] = b.x; fy1[tid] = b.y; fx2[tid] = b.z; fy2[tid] = b.w;
    fa[tid] = (b.z - b.x) * (b.w - b.y);
  }
  if (tid < PK) al[tid] = (tid < Mk) ? 1 : 0;
  __syncthreads();
  if (tid < 64) {                              // wave-serial greedy, O(M) per kept
    int kept = 0;
    for (int i = 0; i < Mk && kept < MDET; ++i) {
      if (!al[i]) continue;
      if (tid == 0) {
        u64 key = sb[i];
        int idx = c * MDET + kept;
        det[idx] = (key & 0xFFFFFFFF00000000ull) | (u64)(0xFFFFFFFFu - (unsigned)idx);
        aux[idx] = 0xFFFFFFFFu - (unsigned)(key & 0xFFFFFFFFull);
      }
      float x1 = fx1[i], y1 = fy1[i], x2 = fx2[i], y2 = fy2[i], ai = fa[i];
      for (int j = i + 1 + tid; j < Mk; j += 64) {
        float ix1 = fmaxf(x1, fx1[j]), iy1 = fmaxf(y1, fy1[j]);
        float ix2 = fminf(x2, fx2[j]), iy2 = fminf(y2, fy2[j]);
        float iw = fmaxf(ix2 - ix1, 0.f), ih = fmaxf(iy2 - iy1, 0.f);
        float inter = iw * ih;
        float uni = ai + fa[j] - inter;
        if (inter / fmaxf(uni, 1e-9f) > NTHR) al[j] = 0;
      }
      ++kept;
    }
  }
  __syncthreads();
}

// ---------------- global top-100: stage 9000 keys -> radix-select -> wave sort ----
__global__ __launch_bounds__(1024) void k_final(const int* __restrict__ flags,
                                                const int* __restrict__ counts,
                                                const u64* __restrict__ cand,
                                                const u64* __restrict__ det,
                                                const unsigned* __restrict__ aux,
                                                const float4* __restrict__ anc,
                                                const float4* __restrict__ reg,
                                                const float* __restrict__ ta,
                                                const float* __restrict__ td,
                                                const float* __restrict__ rot,
                                                float* __restrict__ out) {
  extern __shared__ u64 dyn2[];                 // 90112 B
  u64* D = dyn2;                                // 9216 u64 (keys; also fb scratch)
  unsigned* hist = (unsigned*)(D + 9216);       // 2048 u32 (NBF used)
  u64* sel = (u64*)(hist + 2048);               // 1024 u64
  __shared__ unsigned wsum[16], wsuf[16];
  __shared__ int s_B, s_gc, s_gcnt, s_any;

  const int tid = threadIdx.x;
  const int wave = tid >> 6;
  const int lane = tid & 63;
  const unsigned SB = __float_as_uint(STHR);
  const int NTOT = NC * MDET;                   // 9000

  if (tid == 0) { s_any = 0; s_gcnt = 0; }
  __syncthreads();
  if (tid < NC && flags[tid] != 0) s_any = 1;
  __syncthreads();
  if (s_any) {                                  // exact re-do of flagged classes
    for (int c = 0; c < NC; ++c)
      if (flags[c]) fb_class(c, counts, cand, anc, reg, (u64*)det, (unsigned*)aux, dyn2);
    __threadfence();
    __syncthreads();
  }

  for (int t = tid; t < 9216; t += 1024) D[t] = (t < NTOT) ? det[t] : 0ULL;
  for (int t = tid; t < 2048; t += 1024) hist[t] = 0u;
  sel[tid] = 0ULL;
  __syncthreads();

  for (int t = tid; t < NTOT; t += 1024) {
    u64 k = D[t];
    if (k) atomicAdd(&hist[binf((unsigned)(k >> 32), SB)], 1u);
  }
  __syncthreads();

  // hierarchical suffix scan over NBF bins -> threshold bin B with suffix >= MDET
  const int CH = (NBF + 1023) >> 10;
  int clo = tid * CH, chi = min(clo + CH, NBF);
  unsigned s = 0;
  for (int bb = clo; bb < chi; ++bb) s += hist[bb];
  unsigned ss = s;
  for (int d = 1; d < 64; d <<= 1) {
    unsigned v = __shfl_down(ss, d);
    if (lane + d < 64) ss += v;
  }
  if (lane == 0) wsum[wave] = ss;
  __syncthreads();
  if (tid < 16) {
    unsigned t = wsum[tid];
    for (int d = 1; d < 16; d <<= 1) {
      unsigned v = __shfl_down(t, d);
      if (tid + d < 16) t += v;
    }
    wsuf[tid] = t;
  }
  __syncthreads();
  unsigned suff = ss + ((wave < 15) ? wsuf[wave + 1] : 0u);
  unsigned suffn = suff - s;
  if (tid == 0 && wsuf[0] < MDET) { s_B = 0; s_gc = (int)wsuf[0]; }
  if (suff >= MDET && suffn < MDET) {
    unsigned after = suffn;
    int Bf = clo;
    for (int bb = chi - 1; bb >= clo; --bb) {
      after += hist[bb];
      if (after >= MDET) { Bf = bb; break; }
    }
    s_B = Bf; s_gc = (int)after;
  }
  __syncthreads();
  const int B = s_B, gc = s_gc;

  for (int t = tid; t < NTOT; t += 1024) {
    u64 k = D[t];
    if (k && binf((unsigned)(k >> 32), SB) >= B) {
      int p = atomicAdd(&s_gcnt, 1);
      if (p < 1024) sel[p] = k;
    }
  }
  __syncthreads();

  if (gc <= 128) {
    // single-wave 128-sort: 2 regs/lane, no barriers
    if (tid < 64) {
      u64 ea = sel[lane], eb = sel[64 + lane];
      auto CSWL = [&](u64& lo, u64& hi, int ilow, int k) {
        bool tml = ((ilow & k) == 0);
        u64 mx = lo >= hi ? lo : hi, mn = lo >= hi ? hi : lo;
        lo = tml ? mx : mn; hi = tml ? mn : mx;
      };
      auto SH = [&](u64& x, int ibase, int j, int k) {
        u64 p = __shfl_xor(x, j, 64);
        bool tm = ((((ibase | lane) & k) == 0) != ((lane & j) != 0));
        u64 mx = x >= p ? x : p, mn = x >= p ? p : x;
        x = tm ? mx : mn;
      };
      for (int k = 2; k <= 128; k <<= 1) {
        for (int j = k >> 1; j > 0; j <<= 0, j >>= 1) {
          if (j == 64) CSWL(ea, eb, lane, k);
          else { SH(ea, 0, j, k); SH(eb, 64, j, k); }
        }
      }
      sel[lane] = ea; sel[64 + lane] = eb;
    }
    __syncthreads();
  } else {
    int NSf = 128;
    while (NSf < gc && NSf < 1024) NSf <<= 1;
    bitonic_desc(sel, NSf, tid, 1024);
  }

  // gather top-100 outputs (decode box/translation on the fly)
  if (tid < MDET) {
    u64 key = sel[tid];
    bool ok = (key != 0ULL);
    float b0 = -1.f, b1 = -1.f, b2 = -1.f, b3 = -1.f;
    float r0 = -1.f, r1 = -1.f, r2 = -1.f;
    float t0 = -1.f, t1 = -1.f, t2 = -1.f;
    float sc = -1.f, lab = -1.f;
    if (ok) {
      float score = __uint_as_float((unsigned)(key >> 32));
      unsigned idx = 0xFFFFFFFFu - (unsigned)(key & 0xFFFFFFFFull);
      int c = idx / MDET;
      unsigned aidx = aux[idx];
      float4 bb = decode_box(anc[aidx], reg[aidx]);
      b0 = bb.x; b1 = bb.y; b2 = bb.z; b3 = bb.w;
      sc = score; lab = (float)c;
      r0 = rot[aidx*3+0]; r1 = rot[aidx*3+1]; r2 = rot[aidx*3+2];
      float st = ta[aidx*3+2];
      t0 = ta[aidx*3+0] + td[aidx*3+0] * st;
      t1 = ta[aidx*3+1] + td[aidx*3+1] * st;
      t2 = td[aidx*3+2];
    }
    out[tid*4+0] = b0; out[tid*4+1] = b1; out[tid*4+2] = b2; out[tid*4+3] = b3;
    out[400 + tid] = sc;
    out[500 + tid] = lab;
    out[600 + tid*3+0] = r0; out[600 + tid*3+1] = r1; out[600 + tid*3+2] = r2;
    out[900 + tid*3+0] = t0; out[900 + tid*3+1] = t1; out[900 + tid*3+2] = t2;
  }
}

extern "C" void kernel_launch(void* const* d_in, const int* in_sizes, int n_in,
                              void* d_out, int out_size, void* d_ws, size_t ws_size,
                              hipStream_t stream) {
  const float* anchors        = (const float*)d_in[0];
  const float* regression     = (const float*)d_in[1];
  const float* classification = (const float*)d_in[2];
  const float* rotation       = (const float*)d_in[3];
  const float* tanch          = (const float*)d_in[4];
  const float* tdelta         = (const float*)d_in[5];
  float* out = (float*)d_out;

  char* ws = (char*)d_ws;
  size_t off = 0;
  auto alloc = [&](size_t bytes) -> void* {
    void* p = ws + off;
    off += (bytes + 255) & ~(size_t)255;
    return p;
  };
  int*      counts = (int*)alloc(NC * CPAD * 4);
  u64*      cand   = (u64*)alloc((size_t)NC * CMAX * 8);
  u64*      det    = (u64*)alloc((size_t)NC * MDET * 8);
  unsigned* aux    = (unsigned*)alloc((size_t)NC * MDET * 4);
  int*      flags  = (int*)alloc(NC * 4);

  k_zero<<<(NC * CPAD + 255) / 256, 256, 0, stream>>>(counts);
  k_collect<<<2048, 256, 0, stream>>>((const float4*)classification, counts, cand);
  k_classnms<<<NC, 512, 0, stream>>>(counts, cand,
                                     (const float4*)anchors, (const float4*)regression,
                                     det, aux, flags);

  hipFuncSetAttribute(reinterpret_cast<const void*>(k_final),
                      hipFuncAttributeMaxDynamicSharedMemorySize, 90112);
  k_final<<<1, 1024, 90112, stream>>>(flags, counts, cand, det, aux,
                                      (const float4*)anchors, (const float4*)regression,
                                      tanch, tdelta, rotation, out);
}